// Round 2
// baseline (482.318 us; speedup 1.0000x reference)
//
#include <hip/hip_runtime.h>
#include <math.h>

typedef __bf16 bf16_t;
typedef __bf16 bf16x8 __attribute__((ext_vector_type(8)));
typedef __bf16 bf16x4 __attribute__((ext_vector_type(4)));
typedef float  floatx4 __attribute__((ext_vector_type(4)));

#define TT   4096
#define NB   4
#define CD   1024
#define HSZ  64
#define NROW 16384   // NB*TT
#define NEG_BIG (-1e30f)

// ---------------------------------------------------------------------------
// Kernel 1: QKV projection.  q/k/v = x @ W^T, bf16 out in workspace as
// [3][NROW][64] (order q,k,v).  Scale 0.125*log2(e) folded into q.
// Plain padded LDS (stride 48 elems = 96 B), no swizzle.
// ---------------------------------------------------------------------------
__global__ __launch_bounds__(256, 1) void qkv_proj_kernel(
    const float* __restrict__ x,
    const float* __restrict__ Wk,
    const float* __restrict__ Wq,
    const float* __restrict__ Wv,
    bf16_t* __restrict__ qkv)
{
  // 192 rows (3 weights x 64 out-features) x 32 K-cols per chunk, stride 48.
  __shared__ __align__(16) bf16_t wlds[192 * 48];

  const int tid  = threadIdx.x;
  const int lane = tid & 63;
  const int wave = tid >> 6;
  const int mr   = lane & 15;
  const int quad = lane >> 4;
  const int m0   = blockIdx.x * 64 + wave * 16;  // this wave's 16 x-rows

  floatx4 acc[12];
#pragma unroll
  for (int i = 0; i < 12; ++i) acc[i] = (floatx4){0.f, 0.f, 0.f, 0.f};

  const int rbase = tid >> 3;  // 0..31
  const int cg    = tid & 7;   // column group of 4 fp32

  for (int kc = 0; kc < 32; ++kc) {
    __syncthreads();  // previous chunk's reads complete before overwrite
    // ---- stage weight chunk (192 rows x 32 cols) fp32 -> bf16, plain ----
#pragma unroll
    for (int i = 0; i < 6; ++i) {
      const int wsel = i >> 1;                // 0=q,1=k,2=v
      const int wr   = (i & 1) * 32 + rbase;  // 0..63
      const int r    = wsel * 64 + wr;        // 0..191
      const float* wp = (wsel == 0 ? Wq : (wsel == 1 ? Wk : Wv))
                        + (size_t)wr * CD + kc * 32 + cg * 4;
      float4 w4 = *(const float4*)wp;
      bf16x4 w4b;
      w4b[0] = (bf16_t)w4.x; w4b[1] = (bf16_t)w4.y;
      w4b[2] = (bf16_t)w4.z; w4b[3] = (bf16_t)w4.w;
      *(bf16x4*)&wlds[r * 48 + cg * 4] = w4b;   // byte off = 96r + 8cg, 8B ok
    }
    __syncthreads();
    // ---- A fragment straight from global x ----
    const float* xp = x + (size_t)(m0 + mr) * CD + kc * 32 + quad * 8;
    float4 xa = *(const float4*)xp;
    float4 xb = *(const float4*)(xp + 4);
    bf16x8 af;
    af[0]=(bf16_t)xa.x; af[1]=(bf16_t)xa.y; af[2]=(bf16_t)xa.z; af[3]=(bf16_t)xa.w;
    af[4]=(bf16_t)xb.x; af[5]=(bf16_t)xb.y; af[6]=(bf16_t)xb.z; af[7]=(bf16_t)xb.w;
    // ---- 12 n-tiles (3 weights x 4 tiles of 16) ----
#pragma unroll
    for (int t12 = 0; t12 < 12; ++t12) {
      const int r = t12 * 16 + mr;           // B row = out-feature
      bf16x8 bf = *(bf16x8*)&wlds[r * 48 + quad * 8];  // byte 96r+16q, 16B ok
      acc[t12] = __builtin_amdgcn_mfma_f32_16x16x32_bf16(af, bf, acc[t12], 0, 0, 0);
    }
  }

  // ---- epilogue: C/D layout row = quad*4+reg, col = lane&15 ----
  const float qscale = 0.18033688011112042f;  // 0.125 * log2(e)
#pragma unroll
  for (int t12 = 0; t12 < 12; ++t12) {
    const int wsel = t12 >> 2;
    const int nt   = t12 & 3;
    const float sc = (wsel == 0) ? qscale : 1.0f;
    bf16_t* dst = qkv + (size_t)wsel * NROW * HSZ;
#pragma unroll
    for (int r = 0; r < 4; ++r) {
      const int trow = m0 + quad * 4 + r;
      dst[(size_t)trow * HSZ + nt * 16 + mr] = (bf16_t)(acc[t12][r] * sc);
    }
  }
}

// ---------------------------------------------------------------------------
// Kernel 2: causal flash attention.  One block per (64 q-rows, batch).
// 4 waves x 16 Q rows.  Logits already in log2 domain.  Plain padded LDS.
// ---------------------------------------------------------------------------
__global__ __launch_bounds__(256, 1) void attn_kernel(
    const bf16_t* __restrict__ qkv, float* __restrict__ out)
{
  __shared__ __align__(16) bf16_t klds[64 * 72];     // K[kv][h], stride 72
  __shared__ __align__(16) bf16_t vt[64 * 72];       // V^T[h][kv], stride 72
  __shared__ __align__(16) bf16_t plds[4][16 * 72];  // per-wave P, stride 72

  const int tid  = threadIdx.x;
  const int lane = tid & 63;
  const int wave = tid >> 6;
  const int mr   = lane & 15;
  const int quad = lane >> 4;
  const int b    = blockIdx.y;
  const int qt   = blockIdx.x;
  const int q0   = qt * 64;
  const size_t base = (size_t)b * TT * HSZ;

  const bf16_t* qg = qkv;
  const bf16_t* kg = qkv + (size_t)NROW * HSZ;
  const bf16_t* vg = qkv + (size_t)2 * NROW * HSZ;

  const int qrow_w = q0 + wave * 16;

  // Q fragments (A-operand: m = lane&15, k = quad*8+j), kept in registers.
  bf16x8 qf0, qf1;
  {
    const bf16_t* qp = qg + base + (size_t)(qrow_w + mr) * HSZ + quad * 8;
    qf0 = *(const bf16x8*)qp;        // k = quad*8 .. +7
    qf1 = *(const bf16x8*)(qp + 32); // k = 32+quad*8 .. +7
  }

  floatx4 o[4];
#pragma unroll
  for (int i = 0; i < 4; ++i) o[i] = (floatx4){0.f, 0.f, 0.f, 0.f};
  float mst[4] = {NEG_BIG, NEG_BIG, NEG_BIG, NEG_BIG};
  float lst[4] = {0.f, 0.f, 0.f, 0.f};

  for (int kt = 0; kt <= qt; ++kt) {
    const int k0 = kt * 64;
    __syncthreads();  // all waves done reading previous K/V
    // ---- stage K tile: plain granule copy, no swizzle ----
#pragma unroll
    for (int j = 0; j < 2; ++j) {
      const int gi = tid + j * 256;   // 0..511
      const int kv = gi >> 3;         // 0..63
      const int g  = gi & 7;          // granule of 8
      bf16x8 k8 = *(const bf16x8*)(kg + base + (size_t)(k0 + kv) * HSZ + g * 8);
      *(bf16x8*)&klds[kv * 72 + g * 8] = k8;  // byte = 144kv + 16g, 16B ok
    }
    // ---- stage V transposed, fully scalar ----
#pragma unroll
    for (int e = tid; e < 4096; e += 256) {
      const int kv = e >> 6;   // 0..63
      const int h  = e & 63;
      vt[h * 72 + kv] = vg[base + (size_t)(k0 + kv) * HSZ + h];
    }
    __syncthreads();

    // ---- S = Q K^T (16 rows x 64 cols per wave) ----
    floatx4 s[4];
#pragma unroll
    for (int i = 0; i < 4; ++i) s[i] = (floatx4){0.f, 0.f, 0.f, 0.f};
#pragma unroll
    for (int nt = 0; nt < 4; ++nt) {
      const int n = nt * 16 + mr;   // B col = kv row of K
      bf16x8 b0 = *(bf16x8*)&klds[n * 72 + quad * 8];       // k = quad*8..
      bf16x8 b1 = *(bf16x8*)&klds[n * 72 + 32 + quad * 8];  // k = 32+quad*8..
      s[nt] = __builtin_amdgcn_mfma_f32_16x16x32_bf16(qf0, b0, s[nt], 0, 0, 0);
      s[nt] = __builtin_amdgcn_mfma_f32_16x16x32_bf16(qf1, b1, s[nt], 0, 0, 0);
    }

    // ---- causal mask (diagonal tile only) ----
    if (kt == qt) {
#pragma unroll
      for (int nt = 0; nt < 4; ++nt) {
        const int col = nt * 16 + mr;
#pragma unroll
        for (int r = 0; r < 4; ++r) {
          const int row = wave * 16 + quad * 4 + r;
          if (col > row) s[nt][r] = NEG_BIG;
        }
      }
    }

    // ---- online softmax (base-2; scale folded into q) ----
    float ps[4][4];
#pragma unroll
    for (int r = 0; r < 4; ++r) {
      float mx = fmaxf(fmaxf(s[0][r], s[1][r]), fmaxf(s[2][r], s[3][r]));
      mx = fmaxf(mx, __shfl_xor(mx, 1));
      mx = fmaxf(mx, __shfl_xor(mx, 2));
      mx = fmaxf(mx, __shfl_xor(mx, 4));
      mx = fmaxf(mx, __shfl_xor(mx, 8));
      const float mnew  = fmaxf(mst[r], mx);
      const float alpha = exp2f(mst[r] - mnew);
      mst[r] = mnew;
      float rs = 0.f;
#pragma unroll
      for (int nt = 0; nt < 4; ++nt) {
        const float p = exp2f(s[nt][r] - mnew);
        ps[nt][r] = p;
        rs += p;
      }
      rs += __shfl_xor(rs, 1);
      rs += __shfl_xor(rs, 2);
      rs += __shfl_xor(rs, 4);
      rs += __shfl_xor(rs, 8);
      lst[r] = alpha * lst[r] + rs;
#pragma unroll
      for (int nt = 0; nt < 4; ++nt) o[nt][r] *= alpha;
    }

    // ---- P: C-layout -> A-layout via wave-private LDS ----
#pragma unroll
    for (int nt = 0; nt < 4; ++nt)
#pragma unroll
      for (int r = 0; r < 4; ++r)
        plds[wave][(quad * 4 + r) * 72 + nt * 16 + mr] = (bf16_t)ps[nt][r];
    __syncthreads();

    // ---- O += P V ----
#pragma unroll
    for (int kc = 0; kc < 2; ++kc) {
      // A frag: P[m=mr][k = kc*32 + quad*8 + j]
      bf16x8 af = *(bf16x8*)&plds[wave][mr * 72 + kc * 32 + quad * 8];
#pragma unroll
      for (int nt = 0; nt < 4; ++nt) {
        const int h = nt * 16 + mr;  // B col = head dim
        // B frag: V[k][h] = vt[h][k],  k = kc*32 + quad*8 + j
        bf16x8 vf = *(bf16x8*)&vt[h * 72 + kc * 32 + quad * 8];
        o[nt] = __builtin_amdgcn_mfma_f32_16x16x32_bf16(af, vf, o[nt], 0, 0, 0);
      }
    }
  }

  // ---- epilogue ----
  float inv[4];
#pragma unroll
  for (int r = 0; r < 4; ++r) inv[r] = 1.0f / lst[r];
  float* op = out + base;
#pragma unroll
  for (int nt = 0; nt < 4; ++nt)
#pragma unroll
    for (int r = 0; r < 4; ++r)
      op[(size_t)(qrow_w + quad * 4 + r) * HSZ + nt * 16 + mr] = o[nt][r] * inv[r];
}

// ---------------------------------------------------------------------------
extern "C" void kernel_launch(void* const* d_in, const int* in_sizes, int n_in,
                              void* d_out, int out_size, void* d_ws, size_t ws_size,
                              hipStream_t stream) {
  const float* x  = (const float*)d_in[0];
  const float* Wk = (const float*)d_in[1];
  const float* Wq = (const float*)d_in[2];
  const float* Wv = (const float*)d_in[3];
  float* out = (float*)d_out;
  bf16_t* qkv = (bf16_t*)d_ws;  // [3][16384][64] bf16 = 6 MB

  qkv_proj_kernel<<<dim3(256), dim3(256), 0, stream>>>(x, Wk, Wq, Wv, qkv);
  attn_kernel<<<dim3(64, 4), dim3(256), 0, stream>>>(qkv, out);
}

// Round 3
// 264.743 us; speedup vs baseline: 1.8218x; 1.8218x over previous
//
#include <hip/hip_runtime.h>
#include <math.h>

typedef __bf16 bf16_t;
typedef __bf16 bf16x8 __attribute__((ext_vector_type(8)));
typedef __bf16 bf16x4 __attribute__((ext_vector_type(4)));
typedef float  floatx4 __attribute__((ext_vector_type(4)));

#define TT   4096
#define NB   4
#define CD   1024
#define HSZ  64
#define NROW 16384   // NB*TT
#define NEG_BIG (-1e30f)

// workspace element offsets (bf16)
#define WB_OFF   0
#define Q_OFF    196608            // 3*64*1024 weight elems
#define K_OFF    (196608 + 1048576)
#define VT_OFF   (196608 + 2097152)

// ---------------------------------------------------------------------------
// Kernel 0: convert fp32 weights -> bf16, concatenated [q,k,v][64][1024].
// ---------------------------------------------------------------------------
__global__ __launch_bounds__(256, 1) void wcvt_kernel(
    const float* __restrict__ Wk, const float* __restrict__ Wq,
    const float* __restrict__ Wv, bf16_t* __restrict__ Wb)
{
  const int idx = (blockIdx.x * 256 + threadIdx.x) * 4;  // 192 blocks
  const int w   = idx >> 16;        // 65536 elems per weight
  const int off = idx & 65535;
  const float* src = (w == 0) ? Wq : (w == 1) ? Wk : Wv;
  float4 f = *(const float4*)(src + off);
  bf16x4 o;
  o[0] = (bf16_t)f.x; o[1] = (bf16_t)f.y; o[2] = (bf16_t)f.z; o[3] = (bf16_t)f.w;
  *(bf16x4*)(Wb + idx) = o;
}

// ---------------------------------------------------------------------------
// Kernel 1: QKV projection, barrier-free main loop.  Weights read directly
// from global bf16 (L1/L2-hot).  q,k stored [NROW][64]; v stored transposed
// vT[b][h][t].  Scale 0.125*log2(e) folded into q.
// ---------------------------------------------------------------------------
__global__ __launch_bounds__(256, 4) void qkv_proj_kernel(
    const float* __restrict__ x, const bf16_t* __restrict__ Wb,
    bf16_t* __restrict__ qg, bf16_t* __restrict__ kg, bf16_t* __restrict__ vTg)
{
  __shared__ __align__(16) bf16_t vstg[64 * 72];  // v tile for transpose

  const int tid  = threadIdx.x;
  const int lane = tid & 63;
  const int wave = tid >> 6;
  const int mr   = lane & 15;
  const int quad = lane >> 4;
  const int mb   = blockIdx.x * 64;        // block's 64 rows (one batch)
  const int m0   = mb + wave * 16;         // this wave's 16 x-rows

  floatx4 acc[12];
#pragma unroll
  for (int i = 0; i < 12; ++i) acc[i] = (floatx4){0.f, 0.f, 0.f, 0.f};

  for (int kc = 0; kc < 32; ++kc) {
    // A fragment from global x (fp32 -> bf16)
    const float* xp = x + (size_t)(m0 + mr) * CD + kc * 32 + quad * 8;
    float4 xa = *(const float4*)xp;
    float4 xb = *(const float4*)(xp + 4);
    bf16x8 af;
    af[0]=(bf16_t)xa.x; af[1]=(bf16_t)xa.y; af[2]=(bf16_t)xa.z; af[3]=(bf16_t)xa.w;
    af[4]=(bf16_t)xb.x; af[5]=(bf16_t)xb.y; af[6]=(bf16_t)xb.z; af[7]=(bf16_t)xb.w;
    // B fragments straight from global weights; 12 independent acc chains
#pragma unroll
    for (int t12 = 0; t12 < 12; ++t12) {
      const int wsel = t12 >> 2;
      const int nt   = t12 & 3;
      bf16x8 wf = *(const bf16x8*)(Wb + wsel * 65536 +
                                   (size_t)(nt * 16 + mr) * CD + kc * 32 + quad * 8);
      acc[t12] = __builtin_amdgcn_mfma_f32_16x16x32_bf16(af, wf, acc[t12], 0, 0, 0);
    }
  }

  // ---- epilogue.  C/D layout: row = quad*4+reg, col = lane&15 ----
  const float qscale = 0.18033688011112042f;  // 0.125 * log2(e)
#pragma unroll
  for (int t12 = 0; t12 < 8; ++t12) {        // q and k
    const int wsel = t12 >> 2;
    const int nt   = t12 & 3;
    const float sc = (wsel == 0) ? qscale : 1.0f;
    bf16_t* dst = (wsel == 0) ? qg : kg;
#pragma unroll
    for (int r = 0; r < 4; ++r) {
      const int trow = m0 + quad * 4 + r;
      dst[(size_t)trow * HSZ + nt * 16 + mr] = (bf16_t)(acc[t12][r] * sc);
    }
  }
  // v -> LDS tile, then transposed write-out
#pragma unroll
  for (int nt = 0; nt < 4; ++nt)
#pragma unroll
    for (int r = 0; r < 4; ++r)
      vstg[(wave * 16 + quad * 4 + r) * 72 + nt * 16 + mr] = (bf16_t)acc[8 + nt][r];
  __syncthreads();
  {
    const int h   = tid & 63;
    const int seg = tid >> 6;     // 0..3 (16 t's each)
    const int b   = mb >> 12;
    const int t0  = mb & 4095;
    bf16x8 v0, v1;
#pragma unroll
    for (int i = 0; i < 8; ++i) v0[i] = vstg[(seg * 16 + i) * 72 + h];
#pragma unroll
    for (int i = 0; i < 8; ++i) v1[i] = vstg[(seg * 16 + 8 + i) * 72 + h];
    bf16_t* dst = vTg + (size_t)b * HSZ * TT + (size_t)h * TT + t0 + seg * 16;
    *(bf16x8*)dst = v0;
    *(bf16x8*)(dst + 8) = v1;
  }
}

// ---------------------------------------------------------------------------
// Kernel 2: causal flash attention.  One block per (16 q-rows, batch); the 4
// waves split the KV range (kt = wave, wave+4, ...) and combine at the end.
// Barrier-free main loop: K and V^T fragments read directly from global.
// ---------------------------------------------------------------------------
__global__ __launch_bounds__(256, 4) void attn_kernel(
    const bf16_t* __restrict__ qg, const bf16_t* __restrict__ kg,
    const bf16_t* __restrict__ vTg, float* __restrict__ out)
{
  __shared__ float cml[4][16][2];                    // [wave][row][m,l]
  __shared__ float cmbo[4][16][68];                  // scaled partial O, padded
  __shared__ __align__(16) bf16_t plds[4][16 * 72];  // wave-private P

  const int tid  = threadIdx.x;
  const int lane = tid & 63;
  const int wave = tid >> 6;
  const int mr   = lane & 15;
  const int quad = lane >> 4;

  const int bid = blockIdx.x;            // 0..1023
  const int b   = bid & 3;
  const int p   = bid >> 2;              // 0..255
  const int qt  = (p & 1) ? (255 - (p >> 1)) : (p >> 1);  // balance pairing
  const int q0  = qt * 16;
  const size_t baseq = (size_t)b * TT * HSZ;

  // Q fragments (A-layout: m = lane&15, k = quad*8+j) — same rows for all waves
  bf16x8 qf0, qf1;
  {
    const bf16_t* qp = qg + baseq + (size_t)(q0 + mr) * HSZ + quad * 8;
    qf0 = *(const bf16x8*)qp;
    qf1 = *(const bf16x8*)(qp + 32);
  }

  floatx4 o[4];
#pragma unroll
  for (int i = 0; i < 4; ++i) o[i] = (floatx4){0.f, 0.f, 0.f, 0.f};
  float mst[4] = {NEG_BIG, NEG_BIG, NEG_BIG, NEG_BIG};
  float lst[4] = {0.f, 0.f, 0.f, 0.f};

  const int ktmax = qt >> 2;

  for (int kt = wave; kt <= ktmax; kt += 4) {
    const int k0 = kt * 64;

    // ---- S = Q K^T, K fragments from global ----
    floatx4 s[4];
#pragma unroll
    for (int i = 0; i < 4; ++i) s[i] = (floatx4){0.f, 0.f, 0.f, 0.f};
#pragma unroll
    for (int nt = 0; nt < 4; ++nt) {
      const bf16_t* kp = kg + baseq + (size_t)(k0 + nt * 16 + mr) * HSZ + quad * 8;
      bf16x8 b0 = *(const bf16x8*)kp;
      bf16x8 b1 = *(const bf16x8*)(kp + 32);
      s[nt] = __builtin_amdgcn_mfma_f32_16x16x32_bf16(qf0, b0, s[nt], 0, 0, 0);
      s[nt] = __builtin_amdgcn_mfma_f32_16x16x32_bf16(qf1, b1, s[nt], 0, 0, 0);
    }

    // ---- causal mask (last tile only) ----
    if (kt == ktmax) {
#pragma unroll
      for (int nt = 0; nt < 4; ++nt) {
        const int col = k0 + nt * 16 + mr;
#pragma unroll
        for (int r = 0; r < 4; ++r) {
          const int row = q0 + quad * 4 + r;
          if (col > row) s[nt][r] = NEG_BIG;
        }
      }
    }

    // ---- online softmax (base-2; scale folded into q) ----
    float ps[4][4];
#pragma unroll
    for (int r = 0; r < 4; ++r) {
      float mx = fmaxf(fmaxf(s[0][r], s[1][r]), fmaxf(s[2][r], s[3][r]));
      mx = fmaxf(mx, __shfl_xor(mx, 1));
      mx = fmaxf(mx, __shfl_xor(mx, 2));
      mx = fmaxf(mx, __shfl_xor(mx, 4));
      mx = fmaxf(mx, __shfl_xor(mx, 8));
      const float mnew  = fmaxf(mst[r], mx);
      const float alpha = exp2f(mst[r] - mnew);
      mst[r] = mnew;
      float rs = 0.f;
#pragma unroll
      for (int nt = 0; nt < 4; ++nt) {
        const float pv = exp2f(s[nt][r] - mnew);
        ps[nt][r] = pv;
        rs += pv;
      }
      rs += __shfl_xor(rs, 1);
      rs += __shfl_xor(rs, 2);
      rs += __shfl_xor(rs, 4);
      rs += __shfl_xor(rs, 8);
      lst[r] = alpha * lst[r] + rs;
#pragma unroll
      for (int nt = 0; nt < 4; ++nt) o[nt][r] *= alpha;
    }

    // ---- P: C-layout -> A-layout via wave-private LDS (no barrier) ----
#pragma unroll
    for (int nt = 0; nt < 4; ++nt)
#pragma unroll
      for (int r = 0; r < 4; ++r)
        plds[wave][(quad * 4 + r) * 72 + nt * 16 + mr] = (bf16_t)ps[nt][r];

    // ---- O += P V, V^T fragments from global ----
#pragma unroll
    for (int kc = 0; kc < 2; ++kc) {
      bf16x8 af = *(bf16x8*)&plds[wave][mr * 72 + kc * 32 + quad * 8];
#pragma unroll
      for (int nt = 0; nt < 4; ++nt) {
        bf16x8 vf = *(const bf16x8*)(vTg + (size_t)b * HSZ * TT +
                                     (size_t)(nt * 16 + mr) * TT +
                                     k0 + kc * 32 + quad * 8);
        o[nt] = __builtin_amdgcn_mfma_f32_16x16x32_bf16(af, vf, o[nt], 0, 0, 0);
      }
    }
  }

  // ---- combine the 4 waves' partials ----
  if (mr == 0) {
#pragma unroll
    for (int r = 0; r < 4; ++r) {
      cml[wave][quad * 4 + r][0] = mst[r];
      cml[wave][quad * 4 + r][1] = lst[r];
    }
  }
  __syncthreads();
#pragma unroll
  for (int r = 0; r < 4; ++r) {
    const int row = quad * 4 + r;
    const float mstar = fmaxf(fmaxf(cml[0][row][0], cml[1][row][0]),
                              fmaxf(cml[2][row][0], cml[3][row][0]));
    const float scale = exp2f(mst[r] - mstar);
#pragma unroll
    for (int nt = 0; nt < 4; ++nt)
      cmbo[wave][row][nt * 16 + mr] = o[nt][r] * scale;
  }
  __syncthreads();
  {
    const int row = tid >> 4;
    const int c0  = (tid & 15) * 4;
    const float m0_ = cml[0][row][0], m1_ = cml[1][row][0];
    const float m2_ = cml[2][row][0], m3_ = cml[3][row][0];
    const float mstar = fmaxf(fmaxf(m0_, m1_), fmaxf(m2_, m3_));
    const float l = cml[0][row][1] * exp2f(m0_ - mstar) +
                    cml[1][row][1] * exp2f(m1_ - mstar) +
                    cml[2][row][1] * exp2f(m2_ - mstar) +
                    cml[3][row][1] * exp2f(m3_ - mstar);
    float4 a0 = *(float4*)&cmbo[0][row][c0];
    float4 a1 = *(float4*)&cmbo[1][row][c0];
    float4 a2 = *(float4*)&cmbo[2][row][c0];
    float4 a3 = *(float4*)&cmbo[3][row][c0];
    const float invl = 1.0f / l;
    float4 res;
    res.x = (a0.x + a1.x + a2.x + a3.x) * invl;
    res.y = (a0.y + a1.y + a2.y + a3.y) * invl;
    res.z = (a0.z + a1.z + a2.z + a3.z) * invl;
    res.w = (a0.w + a1.w + a2.w + a3.w) * invl;
    *(float4*)(out + baseq + (size_t)(q0 + row) * HSZ + c0) = res;
  }
}

// ---------------------------------------------------------------------------
extern "C" void kernel_launch(void* const* d_in, const int* in_sizes, int n_in,
                              void* d_out, int out_size, void* d_ws, size_t ws_size,
                              hipStream_t stream) {
  const float* x  = (const float*)d_in[0];
  const float* Wk = (const float*)d_in[1];
  const float* Wq = (const float*)d_in[2];
  const float* Wv = (const float*)d_in[3];
  float* out = (float*)d_out;

  bf16_t* ws  = (bf16_t*)d_ws;
  bf16_t* Wb  = ws + WB_OFF;
  bf16_t* qg  = ws + Q_OFF;
  bf16_t* kg  = ws + K_OFF;
  bf16_t* vTg = ws + VT_OFF;

  wcvt_kernel<<<dim3(192), dim3(256), 0, stream>>>(Wk, Wq, Wv, Wb);
  qkv_proj_kernel<<<dim3(256), dim3(256), 0, stream>>>(x, Wb, qg, kg, vTg);
  attn_kernel<<<dim3(1024), dim3(256), 0, stream>>>(qg, kg, vTg, out);
}

// Round 4
// 232.715 us; speedup vs baseline: 2.0726x; 1.1376x over previous
//
#include <hip/hip_runtime.h>
#include <math.h>

typedef __bf16 bf16_t;
typedef __bf16 bf16x8 __attribute__((ext_vector_type(8)));
typedef __bf16 bf16x4 __attribute__((ext_vector_type(4)));
typedef float  floatx4 __attribute__((ext_vector_type(4)));

#define TT   4096
#define CD   1024
#define HSZ  64
#define NROW 16384
#define NEG_BIG (-1e30f)

// workspace element offsets (bf16)
#define WB_OFF 0                         // 196608 elems (12 tiles x 32 kc x 512)
#define Q_OFF  196608
#define K_OFF  (196608 + NROW * HSZ)
#define VT_OFF (196608 + 2 * NROW * HSZ)

// ---------------------------------------------------------------------------
// Kernel 0: fp32 weights -> bf16 in MFMA B-fragment-contiguous layout.
// Tile (t12 = wsel*4+nt, kc) holds 512 elems; elem (lane, j) = W_wsel[n][k],
// n = nt*16 + (lane&15), k = kc*32 + (lane>>4)*8 + j.  A wave's fragment load
// in the proj kernel is then one contiguous 1 KB read.
// ---------------------------------------------------------------------------
__global__ __launch_bounds__(256, 1) void wcvt_kernel(
    const float* __restrict__ Wk, const float* __restrict__ Wq,
    const float* __restrict__ Wv, bf16_t* __restrict__ Wb)
{
  const int t    = blockIdx.x * 256 + threadIdx.x;  // 0..49151 (192 blocks)
  const int e    = t * 4;
  const int tile = e >> 9;
  const int r    = e & 511;
  const int lane = r >> 3;
  const int j0   = r & 7;           // 0 or 4
  const int t12  = tile >> 5;
  const int kc   = tile & 31;
  const int wsel = t12 >> 2;
  const int nt   = t12 & 3;
  const int n    = nt * 16 + (lane & 15);
  const int k    = kc * 32 + (lane >> 4) * 8 + j0;
  const float* src = (wsel == 0) ? Wq : (wsel == 1) ? Wk : Wv;
  float4 f = *(const float4*)(src + n * CD + k);
  bf16x4 o;
  o[0] = (bf16_t)f.x; o[1] = (bf16_t)f.y; o[2] = (bf16_t)f.z; o[3] = (bf16_t)f.w;
  *(bf16x4*)(Wb + e) = o;
}

// ---------------------------------------------------------------------------
// Kernel 1: QKV projection, n-split for occupancy.  1024 blocks x 4 waves;
// block owns 16 x-rows, wave w computes q-tile w, k-tile w, v-tile w.
// Weights read as contiguous fragments (layout above).  v written transposed
// vT[b][h][t].  Scale 0.125*log2(e) folded into q.
// ---------------------------------------------------------------------------
__global__ __launch_bounds__(256, 8) void qkv_proj_kernel(
    const float* __restrict__ x, const bf16_t* __restrict__ Wb,
    bf16_t* __restrict__ qg, bf16_t* __restrict__ kg, bf16_t* __restrict__ vTg)
{
  __shared__ __align__(16) bf16_t vstg[16 * 72];

  const int tid  = threadIdx.x;
  const int lane = tid & 63;
  const int wave = tid >> 6;
  const int mr   = lane & 15;
  const int quad = lane >> 4;
  const int m0   = blockIdx.x * 16;

  floatx4 acc[3];
#pragma unroll
  for (int i = 0; i < 3; ++i) acc[i] = (floatx4){0.f, 0.f, 0.f, 0.f};

  for (int kc = 0; kc < 32; ++kc) {
    const float* xp = x + (size_t)(m0 + mr) * CD + kc * 32 + quad * 8;
    float4 xa = *(const float4*)xp;
    float4 xb = *(const float4*)(xp + 4);
    bf16x8 af;
    af[0]=(bf16_t)xa.x; af[1]=(bf16_t)xa.y; af[2]=(bf16_t)xa.z; af[3]=(bf16_t)xa.w;
    af[4]=(bf16_t)xb.x; af[5]=(bf16_t)xb.y; af[6]=(bf16_t)xb.z; af[7]=(bf16_t)xb.w;
#pragma unroll
    for (int i = 0; i < 3; ++i) {
      const int t12 = i * 4 + wave;
      bf16x8 wf = *(const bf16x8*)(Wb + ((t12 * 32 + kc) << 9) + lane * 8);
      acc[i] = __builtin_amdgcn_mfma_f32_16x16x32_bf16(af, wf, acc[i], 0, 0, 0);
    }
  }

  // ---- epilogue.  C/D: row = quad*4+reg, col = lane&15 ----
  const float qscale = 0.18033688011112042f;  // 0.125 * log2(e)
#pragma unroll
  for (int r = 0; r < 4; ++r) {
    const int trow = m0 + quad * 4 + r;
    qg[(size_t)trow * HSZ + wave * 16 + mr] = (bf16_t)(acc[0][r] * qscale);
    kg[(size_t)trow * HSZ + wave * 16 + mr] = (bf16_t)acc[1][r];
    vstg[(quad * 4 + r) * 72 + wave * 16 + mr] = (bf16_t)acc[2][r];
  }
  __syncthreads();
  {
    const int h    = tid >> 2;
    const int part = tid & 3;
    const int b    = m0 >> 12;
    const int t0   = m0 & 4095;
    bf16x4 v4;
#pragma unroll
    for (int i = 0; i < 4; ++i) v4[i] = vstg[(part * 4 + i) * 72 + h];
    *(bf16x4*)(vTg + (size_t)b * HSZ * TT + (size_t)h * TT + t0 + part * 4) = v4;
  }
}

// ---------------------------------------------------------------------------
// Kernel 2: causal flash attention.  1024 blocks (qt descending = LPT) x 8
// waves; block owns 16 q-rows, waves split KV 8-way, combine at end.
// K prefetched one iteration ahead (in-place refill); V issued at iter top.
// ---------------------------------------------------------------------------
__global__ __launch_bounds__(512, 4) void attn_kernel(
    const bf16_t* __restrict__ qg, const bf16_t* __restrict__ kg,
    const bf16_t* __restrict__ vTg, float* __restrict__ out)
{
  __shared__ float cml[8][16][2];
  __shared__ float cmbo[8][16][68];
  __shared__ __align__(16) bf16_t plds[8][16 * 72];

  const int tid  = threadIdx.x;
  const int lane = tid & 63;
  const int wave = tid >> 6;
  const int mr   = lane & 15;
  const int quad = lane >> 4;

  const int bid = blockIdx.x;            // 0..1023
  const int b   = bid & 3;
  const int qt  = 255 - (bid >> 2);      // heavy blocks first
  const int q0  = qt * 16;
  const size_t baseq = (size_t)b * TT * HSZ;

  const bf16_t* kb = kg  + baseq;
  const bf16_t* vb = vTg + (size_t)b * HSZ * TT;

  // Q fragments (A-layout: m = lane&15, k = quad*8+j)
  bf16x8 qf0, qf1;
  {
    const bf16_t* qp = qg + baseq + (size_t)(q0 + mr) * HSZ + quad * 8;
    qf0 = *(const bf16x8*)qp;
    qf1 = *(const bf16x8*)(qp + 32);
  }

  floatx4 o[4];
#pragma unroll
  for (int i = 0; i < 4; ++i) o[i] = (floatx4){0.f, 0.f, 0.f, 0.f};
  float mst[4] = {NEG_BIG, NEG_BIG, NEG_BIG, NEG_BIG};
  float lst[4] = {0.f, 0.f, 0.f, 0.f};

  const int ktmax = qt >> 2;

  bf16x8 kfa[4], kfb[4];
  int kt = wave;
  if (kt <= ktmax) {
    const int k0 = kt * 64;
#pragma unroll
    for (int nt = 0; nt < 4; ++nt) {
      const bf16_t* kp = kb + (size_t)(k0 + nt * 16 + mr) * HSZ + quad * 8;
      kfa[nt] = *(const bf16x8*)kp;
      kfb[nt] = *(const bf16x8*)(kp + 32);
    }
  }

  for (; kt <= ktmax; kt += 8) {
    const int k0 = kt * 64;

    // ---- V loads for current kt (latency hidden behind S + softmax) ----
    bf16x8 vfa[4], vfb[4];
#pragma unroll
    for (int nt = 0; nt < 4; ++nt) {
      const bf16_t* vp = vb + (size_t)(nt * 16 + mr) * TT + k0 + quad * 8;
      vfa[nt] = *(const bf16x8*)vp;
      vfb[nt] = *(const bf16x8*)(vp + 32);
    }

    // ---- S = Q K^T ----
    floatx4 s[4];
#pragma unroll
    for (int i = 0; i < 4; ++i) s[i] = (floatx4){0.f, 0.f, 0.f, 0.f};
#pragma unroll
    for (int nt = 0; nt < 4; ++nt) {
      s[nt] = __builtin_amdgcn_mfma_f32_16x16x32_bf16(qf0, kfa[nt], s[nt], 0, 0, 0);
      s[nt] = __builtin_amdgcn_mfma_f32_16x16x32_bf16(qf1, kfb[nt], s[nt], 0, 0, 0);
    }

    // ---- refill K fragments for kt+8 (in-place; wave-uniform guard) ----
    if (kt + 8 <= ktmax) {
      const int k0n = k0 + 512;
#pragma unroll
      for (int nt = 0; nt < 4; ++nt) {
        const bf16_t* kp = kb + (size_t)(k0n + nt * 16 + mr) * HSZ + quad * 8;
        kfa[nt] = *(const bf16x8*)kp;
        kfb[nt] = *(const bf16x8*)(kp + 32);
      }
    }

    // ---- causal mask (last tile only) ----
    if (kt == ktmax) {
#pragma unroll
      for (int nt = 0; nt < 4; ++nt) {
        const int col = k0 + nt * 16 + mr;
#pragma unroll
        for (int r = 0; r < 4; ++r) {
          const int row = q0 + quad * 4 + r;
          if (col > row) s[nt][r] = NEG_BIG;
        }
      }
    }

    // ---- online softmax (base-2); overwrite s with p ----
#pragma unroll
    for (int r = 0; r < 4; ++r) {
      float mx = fmaxf(fmaxf(s[0][r], s[1][r]), fmaxf(s[2][r], s[3][r]));
      mx = fmaxf(mx, __shfl_xor(mx, 1));
      mx = fmaxf(mx, __shfl_xor(mx, 2));
      mx = fmaxf(mx, __shfl_xor(mx, 4));
      mx = fmaxf(mx, __shfl_xor(mx, 8));
      const float mnew  = fmaxf(mst[r], mx);
      const float alpha = exp2f(mst[r] - mnew);
      mst[r] = mnew;
      float rs = 0.f;
#pragma unroll
      for (int nt = 0; nt < 4; ++nt) {
        const float pv = exp2f(s[nt][r] - mnew);
        s[nt][r] = pv;
        rs += pv;
      }
      rs += __shfl_xor(rs, 1);
      rs += __shfl_xor(rs, 2);
      rs += __shfl_xor(rs, 4);
      rs += __shfl_xor(rs, 8);
      lst[r] = alpha * lst[r] + rs;
#pragma unroll
      for (int nt = 0; nt < 4; ++nt) o[nt][r] *= alpha;
    }

    // ---- P: C-layout -> A-layout via wave-private LDS ----
#pragma unroll
    for (int nt = 0; nt < 4; ++nt)
#pragma unroll
      for (int r = 0; r < 4; ++r)
        plds[wave][(quad * 4 + r) * 72 + nt * 16 + mr] = (bf16_t)s[nt][r];

    // ---- O += P V ----
#pragma unroll
    for (int kc = 0; kc < 2; ++kc) {
      bf16x8 af = *(bf16x8*)&plds[wave][mr * 72 + kc * 32 + quad * 8];
#pragma unroll
      for (int nt = 0; nt < 4; ++nt) {
        bf16x8 vf = kc ? vfb[nt] : vfa[nt];
        o[nt] = __builtin_amdgcn_mfma_f32_16x16x32_bf16(af, vf, o[nt], 0, 0, 0);
      }
    }
  }

  // ---- combine the 8 waves' partials ----
  if (mr == 0) {
#pragma unroll
    for (int r = 0; r < 4; ++r) {
      cml[wave][quad * 4 + r][0] = mst[r];
      cml[wave][quad * 4 + r][1] = lst[r];
    }
  }
  __syncthreads();
#pragma unroll
  for (int r = 0; r < 4; ++r) {
    const int row = quad * 4 + r;
    float mstar = cml[0][row][0];
#pragma unroll
    for (int i = 1; i < 8; ++i) mstar = fmaxf(mstar, cml[i][row][0]);
    const float scale = exp2f(mst[r] - mstar);
#pragma unroll
    for (int nt = 0; nt < 4; ++nt)
      cmbo[wave][row][nt * 16 + mr] = o[nt][r] * scale;
  }
  __syncthreads();
  {
    const int row = tid >> 5;
    const int c0  = (tid & 31) * 2;
    float mstar = cml[0][row][0];
#pragma unroll
    for (int i = 1; i < 8; ++i) mstar = fmaxf(mstar, cml[i][row][0]);
    float l = 0.f;
#pragma unroll
    for (int i = 0; i < 8; ++i)
      l += cml[i][row][1] * exp2f(cml[i][row][0] - mstar);
    float sx = 0.f, sy = 0.f;
#pragma unroll
    for (int i = 0; i < 8; ++i) {
      float2 v = *(float2*)&cmbo[i][row][c0];
      sx += v.x; sy += v.y;
    }
    const float invl = 1.0f / l;
    float2 res; res.x = sx * invl; res.y = sy * invl;
    *(float2*)(out + baseq + (size_t)(q0 + row) * HSZ + c0) = res;
  }
}

// ---------------------------------------------------------------------------
extern "C" void kernel_launch(void* const* d_in, const int* in_sizes, int n_in,
                              void* d_out, int out_size, void* d_ws, size_t ws_size,
                              hipStream_t stream) {
  const float* x  = (const float*)d_in[0];
  const float* Wk = (const float*)d_in[1];
  const float* Wq = (const float*)d_in[2];
  const float* Wv = (const float*)d_in[3];
  float* out = (float*)d_out;

  bf16_t* ws  = (bf16_t*)d_ws;
  bf16_t* Wb  = ws + WB_OFF;
  bf16_t* qg  = ws + Q_OFF;
  bf16_t* kg  = ws + K_OFF;
  bf16_t* vTg = ws + VT_OFF;

  wcvt_kernel<<<dim3(192), dim3(256), 0, stream>>>(Wk, Wq, Wv, Wb);
  qkv_proj_kernel<<<dim3(1024), dim3(256), 0, stream>>>(x, Wb, qg, kg, vTg);
  attn_kernel<<<dim3(1024), dim3(512), 0, stream>>>(qg, kg, vTg, out);
}

// Round 5
// 229.961 us; speedup vs baseline: 2.0974x; 1.0120x over previous
//
#include <hip/hip_runtime.h>
#include <math.h>

typedef __bf16 bf16_t;
typedef __bf16 bf16x8 __attribute__((ext_vector_type(8)));
typedef __bf16 bf16x4 __attribute__((ext_vector_type(4)));
typedef float  floatx4 __attribute__((ext_vector_type(4)));

#define TT   4096
#define CD   1024
#define HSZ  64
#define NROW 16384
#define NEG_BIG (-1e30f)

// workspace element offsets (bf16)
#define WB_OFF 0                         // 196608 elems (12 tiles x 32 kc x 512)
#define Q_OFF  196608
#define K_OFF  (196608 + NROW * HSZ)
#define VT_OFF (196608 + 2 * NROW * HSZ)

// ---- DPP 16-lane (DPP-row) allreduce helpers: VALU pipe, no DS ops ----
template <int CTRL>
__device__ __forceinline__ float dppf(float x) {
  return __builtin_bit_cast(float,
      __builtin_amdgcn_update_dpp(0, __builtin_bit_cast(int, x),
                                  CTRL, 0xF, 0xF, true));
}
__device__ __forceinline__ float rowmax16(float v) {
  v = fmaxf(v, dppf<0xB1>(v));    // quad_perm [1,0,3,2]  (xor 1)
  v = fmaxf(v, dppf<0x4E>(v));    // quad_perm [2,3,0,1]  (xor 2)
  v = fmaxf(v, dppf<0x124>(v));   // row_ror:4
  v = fmaxf(v, dppf<0x128>(v));   // row_ror:8
  return v;
}
__device__ __forceinline__ float rowsum16(float v) {
  v += dppf<0xB1>(v);
  v += dppf<0x4E>(v);
  v += dppf<0x124>(v);
  v += dppf<0x128>(v);
  return v;
}

// ---------------------------------------------------------------------------
// Kernel 0: fp32 weights -> bf16 in MFMA B-fragment-contiguous layout.
// Tile (t12 = wsel*4+nt, kc) holds 512 elems; elem (lane, j) = W_wsel[n][k],
// n = nt*16 + (lane&15), k = kc*32 + (lane>>4)*8 + j.
// ---------------------------------------------------------------------------
__global__ __launch_bounds__(256, 1) void wcvt_kernel(
    const float* __restrict__ Wk, const float* __restrict__ Wq,
    const float* __restrict__ Wv, bf16_t* __restrict__ Wb)
{
  const int t    = blockIdx.x * 256 + threadIdx.x;  // 192 blocks
  const int e    = t * 4;
  const int tile = e >> 9;
  const int r    = e & 511;
  const int lane = r >> 3;
  const int j0   = r & 7;
  const int t12  = tile >> 5;
  const int kc   = tile & 31;
  const int wsel = t12 >> 2;
  const int nt   = t12 & 3;
  const int n    = nt * 16 + (lane & 15);
  const int k    = kc * 32 + (lane >> 4) * 8 + j0;
  const float* src = (wsel == 0) ? Wq : (wsel == 1) ? Wk : Wv;
  float4 f = *(const float4*)(src + n * CD + k);
  bf16x4 o;
  o[0] = (bf16_t)f.x; o[1] = (bf16_t)f.y; o[2] = (bf16_t)f.z; o[3] = (bf16_t)f.w;
  *(bf16x4*)(Wb + e) = o;
}

// ---------------------------------------------------------------------------
// Kernel 1: QKV projection.  1024 blocks x 4 waves; block owns 16 x-rows,
// wave w computes q/k/v n-tile w.  kc unrolled x2 for MLP.
// ---------------------------------------------------------------------------
__global__ __launch_bounds__(256, 8) void qkv_proj_kernel(
    const float* __restrict__ x, const bf16_t* __restrict__ Wb,
    bf16_t* __restrict__ qg, bf16_t* __restrict__ kg, bf16_t* __restrict__ vTg)
{
  __shared__ __align__(16) bf16_t vstg[16 * 72];

  const int tid  = threadIdx.x;
  const int lane = tid & 63;
  const int wave = tid >> 6;
  const int mr   = lane & 15;
  const int quad = lane >> 4;
  const int m0   = blockIdx.x * 16;

  floatx4 acc[3];
#pragma unroll
  for (int i = 0; i < 3; ++i) acc[i] = (floatx4){0.f, 0.f, 0.f, 0.f};

  for (int kc = 0; kc < 32; kc += 2) {
    // issue all 10 loads for the two sub-iterations up front
    const float* xp = x + (size_t)(m0 + mr) * CD + kc * 32 + quad * 8;
    float4 xa0 = *(const float4*)xp;
    float4 xb0 = *(const float4*)(xp + 4);
    float4 xa1 = *(const float4*)(xp + 32);
    float4 xb1 = *(const float4*)(xp + 36);
    bf16x8 w0[3], w1[3];
#pragma unroll
    for (int i = 0; i < 3; ++i) {
      const int t12 = i * 4 + wave;
      w0[i] = *(const bf16x8*)(Wb + (((t12 * 32 + kc) << 9) + lane * 8));
      w1[i] = *(const bf16x8*)(Wb + (((t12 * 32 + kc + 1) << 9) + lane * 8));
    }
    bf16x8 af0, af1;
    af0[0]=(bf16_t)xa0.x; af0[1]=(bf16_t)xa0.y; af0[2]=(bf16_t)xa0.z; af0[3]=(bf16_t)xa0.w;
    af0[4]=(bf16_t)xb0.x; af0[5]=(bf16_t)xb0.y; af0[6]=(bf16_t)xb0.z; af0[7]=(bf16_t)xb0.w;
    af1[0]=(bf16_t)xa1.x; af1[1]=(bf16_t)xa1.y; af1[2]=(bf16_t)xa1.z; af1[3]=(bf16_t)xa1.w;
    af1[4]=(bf16_t)xb1.x; af1[5]=(bf16_t)xb1.y; af1[6]=(bf16_t)xb1.z; af1[7]=(bf16_t)xb1.w;
#pragma unroll
    for (int i = 0; i < 3; ++i)
      acc[i] = __builtin_amdgcn_mfma_f32_16x16x32_bf16(af0, w0[i], acc[i], 0, 0, 0);
#pragma unroll
    for (int i = 0; i < 3; ++i)
      acc[i] = __builtin_amdgcn_mfma_f32_16x16x32_bf16(af1, w1[i], acc[i], 0, 0, 0);
  }

  // ---- epilogue.  C/D: row = quad*4+reg, col = lane&15 ----
  const float qscale = 0.18033688011112042f;  // 0.125 * log2(e)
#pragma unroll
  for (int r = 0; r < 4; ++r) {
    const int trow = m0 + quad * 4 + r;
    qg[(size_t)trow * HSZ + wave * 16 + mr] = (bf16_t)(acc[0][r] * qscale);
    kg[(size_t)trow * HSZ + wave * 16 + mr] = (bf16_t)acc[1][r];
    vstg[(quad * 4 + r) * 72 + wave * 16 + mr] = (bf16_t)acc[2][r];
  }
  __syncthreads();
  {
    const int h    = tid >> 2;
    const int part = tid & 3;
    const int b    = m0 >> 12;
    const int t0   = m0 & 4095;
    bf16x4 v4;
#pragma unroll
    for (int i = 0; i < 4; ++i) v4[i] = vstg[(part * 4 + i) * 72 + h];
    *(bf16x4*)(vTg + (size_t)b * HSZ * TT + (size_t)h * TT + t0 + part * 4) = v4;
  }
}

// ---------------------------------------------------------------------------
// Kernel 2: causal flash attention.  1024 blocks (qt descending) x 8 waves;
// block owns 16 q-rows, waves split KV 8-way, combine at end.
// Softmax reductions via DPP (VALU) — no shuffles in the main loop.
// LDS: plds (main loop) unioned with cmbo (combine) -> 35 KB, 4 blocks/CU.
// ---------------------------------------------------------------------------
__global__ __launch_bounds__(512, 4) void attn_kernel(
    const bf16_t* __restrict__ qg, const bf16_t* __restrict__ kg,
    const bf16_t* __restrict__ vTg, float* __restrict__ out)
{
  __shared__ __align__(16) char smem[34816 + 1024];
  bf16_t* plds = (bf16_t*)smem;                          // [8][16*72] = 18432 B
  float (*cmbo)[16][68] = (float (*)[16][68])smem;       // [8][16][68] = 34816 B
  float (*cml)[16][2]   = (float (*)[16][2])(smem + 34816);  // 1024 B

  const int tid  = threadIdx.x;
  const int lane = tid & 63;
  const int wave = tid >> 6;
  const int mr   = lane & 15;
  const int quad = lane >> 4;

  const int bid = blockIdx.x;            // 0..1023
  const int b   = bid & 3;
  const int qt  = 255 - (bid >> 2);      // heavy blocks first
  const int q0  = qt * 16;
  const size_t baseq = (size_t)b * TT * HSZ;

  const bf16_t* kb = kg  + baseq;
  const bf16_t* vb = vTg + (size_t)b * HSZ * TT;

  // Q fragments (A-layout: m = lane&15, k = quad*8+j)
  bf16x8 qf0, qf1;
  {
    const bf16_t* qp = qg + baseq + (size_t)(q0 + mr) * HSZ + quad * 8;
    qf0 = *(const bf16x8*)qp;
    qf1 = *(const bf16x8*)(qp + 32);
  }

  floatx4 o[4];
#pragma unroll
  for (int i = 0; i < 4; ++i) o[i] = (floatx4){0.f, 0.f, 0.f, 0.f};
  float mst[4] = {NEG_BIG, NEG_BIG, NEG_BIG, NEG_BIG};
  float lst[4] = {0.f, 0.f, 0.f, 0.f};

  const int ktmax = qt >> 2;

  bf16x8 kfa[4], kfb[4];
  int kt = wave;
  if (kt <= ktmax) {
    const int k0 = kt * 64;
#pragma unroll
    for (int nt = 0; nt < 4; ++nt) {
      const bf16_t* kp = kb + (size_t)(k0 + nt * 16 + mr) * HSZ + quad * 8;
      kfa[nt] = *(const bf16x8*)kp;
      kfb[nt] = *(const bf16x8*)(kp + 32);
    }
  }

  for (; kt <= ktmax; kt += 8) {
    const int k0 = kt * 64;

    // ---- V loads for current kt (latency hidden behind S + softmax) ----
    bf16x8 vfa[4], vfb[4];
#pragma unroll
    for (int nt = 0; nt < 4; ++nt) {
      const bf16_t* vp = vb + (size_t)(nt * 16 + mr) * TT + k0 + quad * 8;
      vfa[nt] = *(const bf16x8*)vp;
      vfb[nt] = *(const bf16x8*)(vp + 32);
    }

    // ---- S = Q K^T ----
    floatx4 s[4];
#pragma unroll
    for (int i = 0; i < 4; ++i) s[i] = (floatx4){0.f, 0.f, 0.f, 0.f};
#pragma unroll
    for (int nt = 0; nt < 4; ++nt) {
      s[nt] = __builtin_amdgcn_mfma_f32_16x16x32_bf16(qf0, kfa[nt], s[nt], 0, 0, 0);
      s[nt] = __builtin_amdgcn_mfma_f32_16x16x32_bf16(qf1, kfb[nt], s[nt], 0, 0, 0);
    }

    // ---- refill K fragments for kt+8 (in-place; wave-uniform guard) ----
    if (kt + 8 <= ktmax) {
      const int k0n = k0 + 512;
#pragma unroll
      for (int nt = 0; nt < 4; ++nt) {
        const bf16_t* kp = kb + (size_t)(k0n + nt * 16 + mr) * HSZ + quad * 8;
        kfa[nt] = *(const bf16x8*)kp;
        kfb[nt] = *(const bf16x8*)(kp + 32);
      }
    }

    // ---- causal mask (last tile only) ----
    if (kt == ktmax) {
#pragma unroll
      for (int nt = 0; nt < 4; ++nt) {
        const int col = k0 + nt * 16 + mr;
#pragma unroll
        for (int r = 0; r < 4; ++r) {
          const int row = q0 + quad * 4 + r;
          if (col > row) s[nt][r] = NEG_BIG;
        }
      }
    }

    // ---- online softmax (base-2), DPP row reductions ----
#pragma unroll
    for (int r = 0; r < 4; ++r) {
      float mx = fmaxf(fmaxf(s[0][r], s[1][r]), fmaxf(s[2][r], s[3][r]));
      mx = rowmax16(mx);
      const float mnew  = fmaxf(mst[r], mx);
      const float alpha = exp2f(mst[r] - mnew);
      mst[r] = mnew;
      float rs = 0.f;
#pragma unroll
      for (int nt = 0; nt < 4; ++nt) {
        const float pv = exp2f(s[nt][r] - mnew);
        s[nt][r] = pv;
        rs += pv;
      }
      rs = rowsum16(rs);
      lst[r] = alpha * lst[r] + rs;
#pragma unroll
      for (int nt = 0; nt < 4; ++nt) o[nt][r] *= alpha;
    }

    // ---- P: C-layout -> A-layout via wave-private LDS ----
#pragma unroll
    for (int nt = 0; nt < 4; ++nt)
#pragma unroll
      for (int r = 0; r < 4; ++r)
        plds[wave * 1152 + (quad * 4 + r) * 72 + nt * 16 + mr] = (bf16_t)s[nt][r];

    // ---- O += P V ----
#pragma unroll
    for (int kc = 0; kc < 2; ++kc) {
      bf16x8 af = *(bf16x8*)&plds[wave * 1152 + mr * 72 + kc * 32 + quad * 8];
#pragma unroll
      for (int nt = 0; nt < 4; ++nt) {
        bf16x8 vf = kc ? vfb[nt] : vfa[nt];
        o[nt] = __builtin_amdgcn_mfma_f32_16x16x32_bf16(af, vf, o[nt], 0, 0, 0);
      }
    }
  }

  // ---- combine the 8 waves' partials ----
  if (mr == 0) {
#pragma unroll
    for (int r = 0; r < 4; ++r) {
      cml[wave][quad * 4 + r][0] = mst[r];
      cml[wave][quad * 4 + r][1] = lst[r];
    }
  }
  __syncthreads();   // cml visible; all plds reads drained (cmbo may overwrite)
#pragma unroll
  for (int r = 0; r < 4; ++r) {
    const int row = quad * 4 + r;
    float mstar = cml[0][row][0];
#pragma unroll
    for (int i = 1; i < 8; ++i) mstar = fmaxf(mstar, cml[i][row][0]);
    const float scale = exp2f(mst[r] - mstar);
#pragma unroll
    for (int nt = 0; nt < 4; ++nt)
      cmbo[wave][row][nt * 16 + mr] = o[nt][r] * scale;
  }
  __syncthreads();
  {
    const int row = tid >> 5;
    const int c0  = (tid & 31) * 2;
    float mstar = cml[0][row][0];
#pragma unroll
    for (int i = 1; i < 8; ++i) mstar = fmaxf(mstar, cml[i][row][0]);
    float l = 0.f;
#pragma unroll
    for (int i = 0; i < 8; ++i)
      l += cml[i][row][1] * exp2f(cml[i][row][0] - mstar);
    float sx = 0.f, sy = 0.f;
#pragma unroll
    for (int i = 0; i < 8; ++i) {
      float2 v = *(float2*)&cmbo[i][row][c0];
      sx += v.x; sy += v.y;
    }
    const float invl = 1.0f / l;
    float2 res; res.x = sx * invl; res.y = sy * invl;
    *(float2*)(out + baseq + (size_t)(q0 + row) * HSZ + c0) = res;
  }
}

// ---------------------------------------------------------------------------
extern "C" void kernel_launch(void* const* d_in, const int* in_sizes, int n_in,
                              void* d_out, int out_size, void* d_ws, size_t ws_size,
                              hipStream_t stream) {
  const float* x  = (const float*)d_in[0];
  const float* Wk = (const float*)d_in[1];
  const float* Wq = (const float*)d_in[2];
  const float* Wv = (const float*)d_in[3];
  float* out = (float*)d_out;

  bf16_t* ws  = (bf16_t*)d_ws;
  bf16_t* Wb  = ws + WB_OFF;
  bf16_t* qg  = ws + Q_OFF;
  bf16_t* kg  = ws + K_OFF;
  bf16_t* vTg = ws + VT_OFF;

  wcvt_kernel<<<dim3(192), dim3(256), 0, stream>>>(Wk, Wq, Wv, Wb);
  qkv_proj_kernel<<<dim3(1024), dim3(256), 0, stream>>>(x, Wb, qg, kg, vTg);
  attn_kernel<<<dim3(1024), dim3(512), 0, stream>>>(qg, kg, vTg, out);
}

// Round 6
// 185.922 us; speedup vs baseline: 2.5942x; 1.2369x over previous
//
#include <hip/hip_runtime.h>
#include <math.h>

typedef __bf16 bf16_t;
typedef __bf16 bf16x8 __attribute__((ext_vector_type(8)));
typedef __bf16 bf16x4 __attribute__((ext_vector_type(4)));
typedef float  floatx4 __attribute__((ext_vector_type(4)));

#define TT   4096
#define CD   1024
#define HSZ  64
#define NROW 16384
#define NEG_BIG (-1e30f)

// workspace element offsets (bf16)
#define WB_OFF 0                         // 196608 elems (12 tiles x 32 kc x 512)
#define Q_OFF  196608
#define K_OFF  (196608 + NROW * HSZ)
#define VT_OFF (196608 + 2 * NROW * HSZ)

#if __has_builtin(__builtin_amdgcn_exp2f)
__device__ __forceinline__ float fexp2(float x) { return __builtin_amdgcn_exp2f(x); }
#else
__device__ __forceinline__ float fexp2(float x) { return exp2f(x); }
#endif

// ---- DPP 16-lane allreduce helpers (VALU pipe) ----
template <int CTRL>
__device__ __forceinline__ float dppf(float x) {
  return __builtin_bit_cast(float,
      __builtin_amdgcn_update_dpp(0, __builtin_bit_cast(int, x),
                                  CTRL, 0xF, 0xF, true));
}
__device__ __forceinline__ float rowmax16(float v) {
  v = fmaxf(v, dppf<0xB1>(v));    // quad_perm xor 1
  v = fmaxf(v, dppf<0x4E>(v));    // quad_perm xor 2
  v = fmaxf(v, dppf<0x124>(v));   // row_ror:4
  v = fmaxf(v, dppf<0x128>(v));   // row_ror:8
  return v;
}
__device__ __forceinline__ float rowsum16(float v) {
  v += dppf<0xB1>(v);
  v += dppf<0x4E>(v);
  v += dppf<0x124>(v);
  v += dppf<0x128>(v);
  return v;
}

// ---------------------------------------------------------------------------
// Kernel 0: fp32 weights -> bf16 in MFMA B-fragment-contiguous layout.
// ---------------------------------------------------------------------------
__global__ __launch_bounds__(256, 1) void wcvt_kernel(
    const float* __restrict__ Wk, const float* __restrict__ Wq,
    const float* __restrict__ Wv, bf16_t* __restrict__ Wb)
{
  const int t    = blockIdx.x * 256 + threadIdx.x;  // 192 blocks
  const int e    = t * 4;
  const int tile = e >> 9;
  const int r    = e & 511;
  const int lane = r >> 3;
  const int j0   = r & 7;
  const int t12  = tile >> 5;
  const int kc   = tile & 31;
  const int wsel = t12 >> 2;
  const int nt   = t12 & 3;
  const int n    = nt * 16 + (lane & 15);
  const int k    = kc * 32 + (lane >> 4) * 8 + j0;
  const float* src = (wsel == 0) ? Wq : (wsel == 1) ? Wk : Wv;
  float4 f = *(const float4*)(src + n * CD + k);
  bf16x4 o;
  o[0] = (bf16_t)f.x; o[1] = (bf16_t)f.y; o[2] = (bf16_t)f.z; o[3] = (bf16_t)f.w;
  *(bf16x4*)(Wb + e) = o;
}

// ---------------------------------------------------------------------------
// Kernel 1: QKV projection.  1024 blocks x 4 waves; block owns 16 x-rows.
// x staged into LDS via fully-coalesced 4KB row loads (one instr per row),
// A-fragments from LDS (stride 1040 -> 4-way max).  W frags from global
// (fragment-contiguous).  vT written transposed.
// ---------------------------------------------------------------------------
__global__ __launch_bounds__(256, 4) void qkv_proj_kernel(
    const float* __restrict__ x, const bf16_t* __restrict__ Wb,
    bf16_t* __restrict__ qg, bf16_t* __restrict__ kg, bf16_t* __restrict__ vTg)
{
  __shared__ __align__(16) bf16_t xs[16 * 1040];   // 33.3 KB
  __shared__ __align__(16) bf16_t vstg[16 * 72];

  const int tid  = threadIdx.x;
  const int lane = tid & 63;
  const int wave = tid >> 6;
  const int mr   = lane & 15;
  const int quad = lane >> 4;
  const int m0   = blockIdx.x * 16;

  // ---- stage x: instr i reads row i contiguously (256 thr x 16 B = 4 KB) ----
#pragma unroll
  for (int i = 0; i < 16; ++i) {
    float4 f = *(const float4*)(x + (size_t)(m0 + i) * CD + tid * 4);
    bf16x4 v;
    v[0] = (bf16_t)f.x; v[1] = (bf16_t)f.y; v[2] = (bf16_t)f.z; v[3] = (bf16_t)f.w;
    *(bf16x4*)&xs[i * 1040 + tid * 4] = v;
  }
  __syncthreads();

  floatx4 acc[3];
#pragma unroll
  for (int i = 0; i < 3; ++i) acc[i] = (floatx4){0.f, 0.f, 0.f, 0.f};

#pragma unroll 2
  for (int kc = 0; kc < 32; ++kc) {
    bf16x8 af = *(bf16x8*)&xs[mr * 1040 + kc * 32 + quad * 8];
#pragma unroll
    for (int i = 0; i < 3; ++i) {
      const int t12 = i * 4 + wave;
      bf16x8 wf = *(const bf16x8*)(Wb + (((t12 * 32 + kc) << 9) + lane * 8));
      acc[i] = __builtin_amdgcn_mfma_f32_16x16x32_bf16(af, wf, acc[i], 0, 0, 0);
    }
  }

  // ---- epilogue.  C/D: row = quad*4+reg, col = lane&15 ----
  const float qscale = 0.18033688011112042f;  // 0.125 * log2(e)
#pragma unroll
  for (int r = 0; r < 4; ++r) {
    const int trow = m0 + quad * 4 + r;
    qg[(size_t)trow * HSZ + wave * 16 + mr] = (bf16_t)(acc[0][r] * qscale);
    kg[(size_t)trow * HSZ + wave * 16 + mr] = (bf16_t)acc[1][r];
    vstg[(quad * 4 + r) * 72 + wave * 16 + mr] = (bf16_t)acc[2][r];
  }
  __syncthreads();
  {
    const int h    = tid >> 2;
    const int part = tid & 3;
    const int b    = m0 >> 12;
    const int t0   = m0 & 4095;
    bf16x4 v4;
#pragma unroll
    for (int i = 0; i < 4; ++i) v4[i] = vstg[(part * 4 + i) * 72 + h];
    *(bf16x4*)(vTg + (size_t)b * HSZ * TT + (size_t)h * TT + t0 + part * 4) = v4;
  }
}

// ---------------------------------------------------------------------------
// Kernel 2: causal flash attention, pair-balanced.  512 blocks x 8 waves.
// Block (pr, b) handles q-tiles qtA=pr and qtB=255-pr (16 rows each);
// total KV tiles = (qtA>>2)+(qtB>>2)+2 ~ 66 for EVERY block.  Waves split
// each tile's KV range 8-way; lane-partial l (no per-iter rowsum).
// ---------------------------------------------------------------------------
struct FaState {
  floatx4 o[4];
  float mst[4];
  float lst[4];   // lane-partial
};

__device__ __forceinline__ void fa_tile(
    const bf16_t* __restrict__ kb, const bf16_t* __restrict__ vb,
    int q0, int wave, int mr, int quad, bf16_t* __restrict__ pl,
    const bf16x8& qf0, const bf16x8& qf1, FaState& st)
{
  const int ktmax = q0 >> 6;
  for (int kt = wave; kt <= ktmax; kt += 8) {
    const int k0 = kt * 64;

    bf16x8 vfa[4], vfb[4];
#pragma unroll
    for (int nt = 0; nt < 4; ++nt) {
      const bf16_t* vp = vb + (size_t)(nt * 16 + mr) * TT + k0 + quad * 8;
      vfa[nt] = *(const bf16x8*)vp;
      vfb[nt] = *(const bf16x8*)(vp + 32);
    }

    floatx4 s[4];
#pragma unroll
    for (int i = 0; i < 4; ++i) s[i] = (floatx4){0.f, 0.f, 0.f, 0.f};
#pragma unroll
    for (int nt = 0; nt < 4; ++nt) {
      const bf16_t* kp = kb + (size_t)(k0 + nt * 16 + mr) * HSZ + quad * 8;
      bf16x8 b0 = *(const bf16x8*)kp;
      bf16x8 b1 = *(const bf16x8*)(kp + 32);
      s[nt] = __builtin_amdgcn_mfma_f32_16x16x32_bf16(qf0, b0, s[nt], 0, 0, 0);
      s[nt] = __builtin_amdgcn_mfma_f32_16x16x32_bf16(qf1, b1, s[nt], 0, 0, 0);
    }

    if (kt == ktmax) {
#pragma unroll
      for (int nt = 0; nt < 4; ++nt) {
        const int col = k0 + nt * 16 + mr;
#pragma unroll
        for (int r = 0; r < 4; ++r) {
          const int row = q0 + quad * 4 + r;
          if (col > row) s[nt][r] = NEG_BIG;
        }
      }
    }

#pragma unroll
    for (int r = 0; r < 4; ++r) {
      float mx = fmaxf(fmaxf(s[0][r], s[1][r]), fmaxf(s[2][r], s[3][r]));
      mx = rowmax16(mx);
      const float mnew  = fmaxf(st.mst[r], mx);
      const float alpha = fexp2(st.mst[r] - mnew);
      st.mst[r] = mnew;
      float rs = 0.f;
#pragma unroll
      for (int nt = 0; nt < 4; ++nt) {
        const float pv = fexp2(s[nt][r] - mnew);
        s[nt][r] = pv;
        rs += pv;
      }
      st.lst[r] = alpha * st.lst[r] + rs;   // lane-partial, no reduce
#pragma unroll
      for (int nt = 0; nt < 4; ++nt) st.o[nt][r] *= alpha;
    }

#pragma unroll
    for (int nt = 0; nt < 4; ++nt)
#pragma unroll
      for (int r = 0; r < 4; ++r)
        pl[(quad * 4 + r) * 72 + nt * 16 + mr] = (bf16_t)s[nt][r];

#pragma unroll
    for (int kc = 0; kc < 2; ++kc) {
      bf16x8 af = *(bf16x8*)&pl[mr * 72 + kc * 32 + quad * 8];
#pragma unroll
      for (int nt = 0; nt < 4; ++nt) {
        bf16x8 vf = kc ? vfb[nt] : vfa[nt];
        st.o[nt] = __builtin_amdgcn_mfma_f32_16x16x32_bf16(af, vf, st.o[nt], 0, 0, 0);
      }
    }
  }
}

__device__ __forceinline__ void fa_combine(
    float* __restrict__ outp, int q0, int tid, int wave, int mr, int quad,
    float (*cml)[16][2], float (*cmbo)[16][68], FaState& st)
{
  // reduce lane-partial l, publish (m, l)
  float lsum[4];
#pragma unroll
  for (int r = 0; r < 4; ++r) lsum[r] = rowsum16(st.lst[r]);
  if (mr == 0) {
#pragma unroll
    for (int r = 0; r < 4; ++r) {
      cml[wave][quad * 4 + r][0] = st.mst[r];
      cml[wave][quad * 4 + r][1] = lsum[r];
    }
  }
  __syncthreads();
#pragma unroll
  for (int r = 0; r < 4; ++r) {
    const int row = quad * 4 + r;
    float mstar = cml[0][row][0];
#pragma unroll
    for (int i = 1; i < 8; ++i) mstar = fmaxf(mstar, cml[i][row][0]);
    const float scale = fexp2(st.mst[r] - mstar);
#pragma unroll
    for (int nt = 0; nt < 4; ++nt)
      cmbo[wave][row][nt * 16 + mr] = st.o[nt][r] * scale;
  }
  __syncthreads();
  {
    const int row = tid >> 5;          // 512 thr: 16 rows x 32
    const int c0  = (tid & 31) * 2;
    float mstar = cml[0][row][0];
#pragma unroll
    for (int i = 1; i < 8; ++i) mstar = fmaxf(mstar, cml[i][row][0]);
    float l = 0.f;
#pragma unroll
    for (int i = 0; i < 8; ++i)
      l += cml[i][row][1] * fexp2(cml[i][row][0] - mstar);
    float sx = 0.f, sy = 0.f;
#pragma unroll
    for (int i = 0; i < 8; ++i) {
      float2 v = *(float2*)&cmbo[i][row][c0];
      sx += v.x; sy += v.y;
    }
    const float invl = 1.0f / l;
    float2 res; res.x = sx * invl; res.y = sy * invl;
    *(float2*)(outp + (size_t)(q0 + row) * HSZ + c0) = res;
  }
  __syncthreads();   // allow cml/cmbo reuse by the next tile
}

__global__ __launch_bounds__(512, 4) void attn_kernel(
    const bf16_t* __restrict__ qg, const bf16_t* __restrict__ kg,
    const bf16_t* __restrict__ vTg, float* __restrict__ out)
{
  __shared__ __align__(16) char smem[34816];       // plds U cmbo
  __shared__ float cmlA[8][16][2], cmlB[8][16][2];
  bf16_t* plds = (bf16_t*)smem;                    // [8][16*72] = 18432 B
  float (*cmbo)[16][68] = (float (*)[16][68])smem; // [8][16][68] = 34816 B

  const int tid  = threadIdx.x;
  const int lane = tid & 63;
  const int wave = tid >> 6;
  const int mr   = lane & 15;
  const int quad = lane >> 4;

  const int bid = blockIdx.x;          // 0..511
  const int b   = bid & 3;
  const int pr  = bid >> 2;            // 0..127
  const int qtA = pr;
  const int qtB = 255 - pr;
  const int q0A = qtA * 16;
  const int q0B = qtB * 16;
  const size_t baseq = (size_t)b * TT * HSZ;

  const bf16_t* kb = kg  + baseq;
  const bf16_t* vb = vTg + (size_t)b * HSZ * TT;
  bf16_t* pl = plds + wave * 1152;

  bf16x8 qfA0, qfA1, qfB0, qfB1;
  {
    const bf16_t* qp = qg + baseq + (size_t)(q0A + mr) * HSZ + quad * 8;
    qfA0 = *(const bf16x8*)qp;
    qfA1 = *(const bf16x8*)(qp + 32);
    const bf16_t* qp2 = qg + baseq + (size_t)(q0B + mr) * HSZ + quad * 8;
    qfB0 = *(const bf16x8*)qp2;
    qfB1 = *(const bf16x8*)(qp2 + 32);
  }

  FaState stA, stB;
#pragma unroll
  for (int i = 0; i < 4; ++i) {
    stA.o[i] = (floatx4){0.f, 0.f, 0.f, 0.f};
    stB.o[i] = (floatx4){0.f, 0.f, 0.f, 0.f};
    stA.mst[i] = NEG_BIG; stB.mst[i] = NEG_BIG;
    stA.lst[i] = 0.f;     stB.lst[i] = 0.f;
  }

  fa_tile(kb, vb, q0A, wave, mr, quad, pl, qfA0, qfA1, stA);
  fa_tile(kb, vb, q0B, wave, mr, quad, pl, qfB0, qfB1, stB);

  __syncthreads();   // everyone done with plds before cmbo overwrites it
  fa_combine(out + baseq, q0A, tid, wave, mr, quad, cmlA, cmbo, stA);
  fa_combine(out + baseq, q0B, tid, wave, mr, quad, cmlB, cmbo, stB);
}

// ---------------------------------------------------------------------------
extern "C" void kernel_launch(void* const* d_in, const int* in_sizes, int n_in,
                              void* d_out, int out_size, void* d_ws, size_t ws_size,
                              hipStream_t stream) {
  const float* x  = (const float*)d_in[0];
  const float* Wk = (const float*)d_in[1];
  const float* Wq = (const float*)d_in[2];
  const float* Wv = (const float*)d_in[3];
  float* out = (float*)d_out;

  bf16_t* ws  = (bf16_t*)d_ws;
  bf16_t* Wb  = ws + WB_OFF;
  bf16_t* qg  = ws + Q_OFF;
  bf16_t* kg  = ws + K_OFF;
  bf16_t* vTg = ws + VT_OFF;

  wcvt_kernel<<<dim3(192), dim3(256), 0, stream>>>(Wk, Wq, Wv, Wb);
  qkv_proj_kernel<<<dim3(1024), dim3(256), 0, stream>>>(x, Wb, qg, kg, vTg);
  attn_kernel<<<dim3(512), dim3(512), 0, stream>>>(qg, kg, vTg, out);
}

// Round 7
// 183.936 us; speedup vs baseline: 2.6222x; 1.0108x over previous
//
#include <hip/hip_runtime.h>
#include <math.h>

typedef __bf16 bf16_t;
typedef __bf16 bf16x8 __attribute__((ext_vector_type(8)));
typedef __bf16 bf16x4 __attribute__((ext_vector_type(4)));
typedef float  floatx4 __attribute__((ext_vector_type(4)));

#define TT   4096
#define CD   1024
#define HSZ  64
#define NROW 16384
#define NEG_BIG (-1e30f)

// workspace element offsets (bf16)
#define WB_OFF 0
#define Q_OFF  196608
#define K_OFF  (196608 + NROW * HSZ)
#define VT_OFF (196608 + 2 * NROW * HSZ)

#if __has_builtin(__builtin_amdgcn_exp2f)
__device__ __forceinline__ float fexp2(float x) { return __builtin_amdgcn_exp2f(x); }
#else
__device__ __forceinline__ float fexp2(float x) { return exp2f(x); }
#endif

// ---- DPP 16-lane allreduce (VALU pipe) ----
template <int CTRL>
__device__ __forceinline__ float dppf(float x) {
  return __builtin_bit_cast(float,
      __builtin_amdgcn_update_dpp(0, __builtin_bit_cast(int, x),
                                  CTRL, 0xF, 0xF, true));
}
__device__ __forceinline__ float rowmax16(float v) {
  v = fmaxf(v, dppf<0xB1>(v));
  v = fmaxf(v, dppf<0x4E>(v));
  v = fmaxf(v, dppf<0x124>(v));
  v = fmaxf(v, dppf<0x128>(v));
  return v;
}
__device__ __forceinline__ float rowsum16(float v) {
  v += dppf<0xB1>(v);
  v += dppf<0x4E>(v);
  v += dppf<0x124>(v);
  v += dppf<0x128>(v);
  return v;
}

// ---------------------------------------------------------------------------
// Kernel 0: fp32 weights -> bf16 in MFMA B-fragment-contiguous layout.
// ---------------------------------------------------------------------------
__global__ __launch_bounds__(256, 1) void wcvt_kernel(
    const float* __restrict__ Wk, const float* __restrict__ Wq,
    const float* __restrict__ Wv, bf16_t* __restrict__ Wb)
{
  const int t    = blockIdx.x * 256 + threadIdx.x;
  const int e    = t * 4;
  const int tile = e >> 9;
  const int r    = e & 511;
  const int lane = r >> 3;
  const int j0   = r & 7;
  const int t12  = tile >> 5;
  const int kc   = tile & 31;
  const int wsel = t12 >> 2;
  const int nt   = t12 & 3;
  const int n    = nt * 16 + (lane & 15);
  const int k    = kc * 32 + (lane >> 4) * 8 + j0;
  const float* src = (wsel == 0) ? Wq : (wsel == 1) ? Wk : Wv;
  float4 f = *(const float4*)(src + n * CD + k);
  bf16x4 o;
  o[0] = (bf16_t)f.x; o[1] = (bf16_t)f.y; o[2] = (bf16_t)f.z; o[3] = (bf16_t)f.w;
  *(bf16x4*)(Wb + e) = o;
}

// ---------------------------------------------------------------------------
// Kernel 1: QKV projection.  1024 blocks x 4 waves; block owns 16 x-rows.
// x LDS-staged coalesced (stride 1048: only free 2-way conflicts).
// W-fragment and x-fragment double-buffered across kc.
// ---------------------------------------------------------------------------
__global__ __launch_bounds__(256, 4) void qkv_proj_kernel(
    const float* __restrict__ x, const bf16_t* __restrict__ Wb,
    bf16_t* __restrict__ qg, bf16_t* __restrict__ kg, bf16_t* __restrict__ vTg)
{
  __shared__ __align__(16) bf16_t xs[16 * 1048];
  __shared__ __align__(16) bf16_t vstg[16 * 72];

  const int tid  = threadIdx.x;
  const int lane = tid & 63;
  const int wave = tid >> 6;
  const int mr   = lane & 15;
  const int quad = lane >> 4;
  const int m0   = blockIdx.x * 16;

#pragma unroll
  for (int i = 0; i < 16; ++i) {
    float4 f = *(const float4*)(x + (size_t)(m0 + i) * CD + tid * 4);
    bf16x4 v;
    v[0] = (bf16_t)f.x; v[1] = (bf16_t)f.y; v[2] = (bf16_t)f.z; v[3] = (bf16_t)f.w;
    *(bf16x4*)&xs[i * 1048 + tid * 4] = v;
  }
  __syncthreads();

  floatx4 acc[3];
#pragma unroll
  for (int i = 0; i < 3; ++i) acc[i] = (floatx4){0.f, 0.f, 0.f, 0.f};

  bf16x8 af = *(bf16x8*)&xs[mr * 1048 + quad * 8];
  bf16x8 wf[3];
#pragma unroll
  for (int i = 0; i < 3; ++i)
    wf[i] = *(const bf16x8*)(Wb + (((i * 4 + wave) * 32) << 9) + lane * 8);

  for (int kc = 0; kc < 32; ++kc) {
    bf16x8 an, wn[3];
    if (kc < 31) {
      an = *(bf16x8*)&xs[mr * 1048 + (kc + 1) * 32 + quad * 8];
#pragma unroll
      for (int i = 0; i < 3; ++i)
        wn[i] = *(const bf16x8*)(Wb + ((((i * 4 + wave) * 32 + kc + 1) << 9)) + lane * 8);
    }
#pragma unroll
    for (int i = 0; i < 3; ++i)
      acc[i] = __builtin_amdgcn_mfma_f32_16x16x32_bf16(af, wf[i], acc[i], 0, 0, 0);
    af = an;
#pragma unroll
    for (int i = 0; i < 3; ++i) wf[i] = wn[i];
  }

  const float qscale = 0.18033688011112042f;  // 0.125 * log2(e)
#pragma unroll
  for (int r = 0; r < 4; ++r) {
    const int trow = m0 + quad * 4 + r;
    qg[(size_t)trow * HSZ + wave * 16 + mr] = (bf16_t)(acc[0][r] * qscale);
    kg[(size_t)trow * HSZ + wave * 16 + mr] = (bf16_t)acc[1][r];
    vstg[(quad * 4 + r) * 72 + wave * 16 + mr] = (bf16_t)acc[2][r];
  }
  __syncthreads();
  {
    const int h    = tid >> 2;
    const int part = tid & 3;
    const int b    = m0 >> 12;
    const int t0   = m0 & 4095;
    bf16x4 v4;
#pragma unroll
    for (int i = 0; i < 4; ++i) v4[i] = vstg[(part * 4 + i) * 72 + h];
    *(bf16x4*)(vTg + (size_t)b * HSZ * TT + (size_t)h * TT + t0 + part * 4) = v4;
  }
}

// ---------------------------------------------------------------------------
// Kernel 2: causal flash attention.  256 blocks x 1024 thr (16 waves).
// Block owns paired 32-row groups (gA=pr, gB=127-pr) of batch b = bid&3
// (pins each XCD to one batch's K/V -> L2-resident).  Waves are partitioned
// between the groups proportionally to KV work (na waves on A, 16-na on B);
// each wave owns 32 q-rows (2 subtiles sharing every K/V fragment load).
// ---------------------------------------------------------------------------
__global__ __launch_bounds__(1024, 4) void attn_kernel(
    const bf16_t* __restrict__ qg, const bf16_t* __restrict__ kg,
    const bf16_t* __restrict__ vTg, float* __restrict__ out)
{
  __shared__ __align__(16) char smem[73728];            // plds U cmbo
  __shared__ float cml[16][16][2];
  bf16_t* plds = (bf16_t*)smem;                         // 16 x 2304 elems
  float (*cmbo)[16][68] = (float (*)[16][68])smem;      // [16][16][68] = 69632 B

  const int tid  = threadIdx.x;
  const int lane = tid & 63;
  const int wave = tid >> 6;     // 0..15
  const int mr   = lane & 15;
  const int quad = lane >> 4;

  const int bid = blockIdx.x;    // 0..255
  const int b   = bid & 3;       // batch; round-robin dispatch pins per XCD
  const int pr  = bid >> 2;      // 0..63
  const int gA  = pr;
  const int gB  = 127 - pr;
  const int nAw = (gA >> 1) + 1; // KV tiles of group A
  const int nBw = (gB >> 1) + 1;
  int na = (16 * nAw + ((nAw + nBw) >> 1)) / (nAw + nBw);
  na = na < 1 ? 1 : (na > 15 ? 15 : na);

  const bool inA   = wave < na;
  const int g      = inA ? gA : gB;
  const int slot   = inA ? wave : wave - na;
  const int nsplit = inA ? na : 16 - na;
  const int q0     = g * 32;
  const int ktmax  = g >> 1;

  const size_t baseq = (size_t)b * TT * HSZ;
  const bf16_t* kb = kg  + baseq;
  const bf16_t* vb = vTg + (size_t)b * HSZ * TT;

  bf16_t* pl0 = plds + wave * 2304;
  bf16_t* pl1 = pl0 + 1152;

  // Q fragments for both subtiles (A-layout: m = lane&15, k = quad*8+j)
  bf16x8 qf[2][2];
#pragma unroll
  for (int s = 0; s < 2; ++s) {
    const bf16_t* qp = qg + baseq + (size_t)(q0 + s * 16 + mr) * HSZ + quad * 8;
    qf[s][0] = *(const bf16x8*)qp;
    qf[s][1] = *(const bf16x8*)(qp + 32);
  }

  floatx4 o0[4], o1[4];
#pragma unroll
  for (int i = 0; i < 4; ++i) {
    o0[i] = (floatx4){0.f, 0.f, 0.f, 0.f};
    o1[i] = (floatx4){0.f, 0.f, 0.f, 0.f};
  }
  float mst[2][4], lst[2][4];
#pragma unroll
  for (int s = 0; s < 2; ++s)
#pragma unroll
    for (int r = 0; r < 4; ++r) { mst[s][r] = NEG_BIG; lst[s][r] = 0.f; }

  for (int kt = slot; kt <= ktmax; kt += nsplit) {
    const int k0 = kt * 64;

    // ---- S for both subtiles from shared K fragments ----
    floatx4 s0[4], s1[4];
#pragma unroll
    for (int i = 0; i < 4; ++i) {
      s0[i] = (floatx4){0.f, 0.f, 0.f, 0.f};
      s1[i] = (floatx4){0.f, 0.f, 0.f, 0.f};
    }
#pragma unroll
    for (int nt = 0; nt < 4; ++nt) {
      const bf16_t* kp = kb + (size_t)(k0 + nt * 16 + mr) * HSZ + quad * 8;
      bf16x8 kb0 = *(const bf16x8*)kp;
      bf16x8 kb1 = *(const bf16x8*)(kp + 32);
      s0[nt] = __builtin_amdgcn_mfma_f32_16x16x32_bf16(qf[0][0], kb0, s0[nt], 0, 0, 0);
      s0[nt] = __builtin_amdgcn_mfma_f32_16x16x32_bf16(qf[0][1], kb1, s0[nt], 0, 0, 0);
      s1[nt] = __builtin_amdgcn_mfma_f32_16x16x32_bf16(qf[1][0], kb0, s1[nt], 0, 0, 0);
      s1[nt] = __builtin_amdgcn_mfma_f32_16x16x32_bf16(qf[1][1], kb1, s1[nt], 0, 0, 0);
    }

    // ---- causal mask (last tile only) ----
    if (kt == ktmax) {
#pragma unroll
      for (int nt = 0; nt < 4; ++nt) {
        const int col = k0 + nt * 16 + mr;
#pragma unroll
        for (int r = 0; r < 4; ++r) {
          const int row0 = q0 + quad * 4 + r;
          if (col > row0)      s0[nt][r] = NEG_BIG;
          if (col > row0 + 16) s1[nt][r] = NEG_BIG;
        }
      }
    }

    // ---- softmax subtile 0 -> P0 ----
#pragma unroll
    for (int r = 0; r < 4; ++r) {
      float mx = fmaxf(fmaxf(s0[0][r], s0[1][r]), fmaxf(s0[2][r], s0[3][r]));
      mx = rowmax16(mx);
      const float mnew  = fmaxf(mst[0][r], mx);
      const float alpha = fexp2(mst[0][r] - mnew);
      mst[0][r] = mnew;
      float rs = 0.f;
#pragma unroll
      for (int nt = 0; nt < 4; ++nt) {
        const float pv = fexp2(s0[nt][r] - mnew);
        s0[nt][r] = pv;
        rs += pv;
      }
      lst[0][r] = alpha * lst[0][r] + rs;
#pragma unroll
      for (int nt = 0; nt < 4; ++nt) o0[nt][r] *= alpha;
    }
#pragma unroll
    for (int nt = 0; nt < 4; ++nt)
#pragma unroll
      for (int r = 0; r < 4; ++r)
        pl0[(quad * 4 + r) * 72 + nt * 16 + mr] = (bf16_t)s0[nt][r];

    // ---- V loads (shared by both subtiles' PV) ----
    bf16x8 vfa[4], vfb[4];
#pragma unroll
    for (int nt = 0; nt < 4; ++nt) {
      const bf16_t* vp = vb + (size_t)(nt * 16 + mr) * TT + k0 + quad * 8;
      vfa[nt] = *(const bf16x8*)vp;
      vfb[nt] = *(const bf16x8*)(vp + 32);
    }

    // ---- softmax subtile 1 -> P1 ----
#pragma unroll
    for (int r = 0; r < 4; ++r) {
      float mx = fmaxf(fmaxf(s1[0][r], s1[1][r]), fmaxf(s1[2][r], s1[3][r]));
      mx = rowmax16(mx);
      const float mnew  = fmaxf(mst[1][r], mx);
      const float alpha = fexp2(mst[1][r] - mnew);
      mst[1][r] = mnew;
      float rs = 0.f;
#pragma unroll
      for (int nt = 0; nt < 4; ++nt) {
        const float pv = fexp2(s1[nt][r] - mnew);
        s1[nt][r] = pv;
        rs += pv;
      }
      lst[1][r] = alpha * lst[1][r] + rs;
#pragma unroll
      for (int nt = 0; nt < 4; ++nt) o1[nt][r] *= alpha;
    }
#pragma unroll
    for (int nt = 0; nt < 4; ++nt)
#pragma unroll
      for (int r = 0; r < 4; ++r)
        pl1[(quad * 4 + r) * 72 + nt * 16 + mr] = (bf16_t)s1[nt][r];

    // ---- O += P V (both subtiles, shared V) ----
#pragma unroll
    for (int kc = 0; kc < 2; ++kc) {
      bf16x8 af0 = *(bf16x8*)&pl0[mr * 72 + kc * 32 + quad * 8];
      bf16x8 af1 = *(bf16x8*)&pl1[mr * 72 + kc * 32 + quad * 8];
#pragma unroll
      for (int nt = 0; nt < 4; ++nt) {
        bf16x8 vf = kc ? vfb[nt] : vfa[nt];
        o0[nt] = __builtin_amdgcn_mfma_f32_16x16x32_bf16(af0, vf, o0[nt], 0, 0, 0);
        o1[nt] = __builtin_amdgcn_mfma_f32_16x16x32_bf16(af1, vf, o1[nt], 0, 0, 0);
      }
    }
  }

  // ---- combine: per group over its wave-slots, one subtile per pass ----
  __syncthreads();   // all PV reads of plds done (cmbo overlays it)
#pragma unroll
  for (int s = 0; s < 2; ++s) {
    float lsum[4];
#pragma unroll
    for (int r = 0; r < 4; ++r) lsum[r] = rowsum16(lst[s][r]);
    if (mr == 0) {
#pragma unroll
      for (int r = 0; r < 4; ++r) {
        cml[wave][quad * 4 + r][0] = mst[s][r];
        cml[wave][quad * 4 + r][1] = lsum[r];
      }
    }
    __syncthreads();
    {
      const int lo = inA ? 0 : na;
      const int hi = inA ? na : 16;
#pragma unroll
      for (int r = 0; r < 4; ++r) {
        const int row = quad * 4 + r;
        float mstar = cml[lo][row][0];
        for (int i = lo + 1; i < hi; ++i) mstar = fmaxf(mstar, cml[i][row][0]);
        const float scale = fexp2(mst[s][r] - mstar);
#pragma unroll
        for (int nt = 0; nt < 4; ++nt)
          cmbo[wave][row][nt * 16 + mr] = (s ? o1[nt][r] : o0[nt][r]) * scale;
      }
    }
    __syncthreads();
    {
      const int grp = tid >> 9;            // 0 = A, 1 = B
      const int row = (tid >> 5) & 15;
      const int c0  = (tid & 31) * 2;
      const int lo  = grp ? na : 0;
      const int hi  = grp ? 16 : na;
      const int gq0 = (grp ? gB : gA) * 32 + s * 16;
      float mstar = cml[lo][row][0];
      for (int i = lo + 1; i < hi; ++i) mstar = fmaxf(mstar, cml[i][row][0]);
      float l = 0.f;
      for (int i = lo; i < hi; ++i)
        l += cml[i][row][1] * fexp2(cml[i][row][0] - mstar);
      float sx = 0.f, sy = 0.f;
      for (int i = lo; i < hi; ++i) {
        float2 v = *(float2*)&cmbo[i][row][c0];
        sx += v.x; sy += v.y;
      }
      const float invl = 1.0f / l;
      float2 res; res.x = sx * invl; res.y = sy * invl;
      *(float2*)(out + baseq + (size_t)(gq0 + row) * HSZ + c0) = res;
    }
    __syncthreads();   // cml/cmbo reused by next pass
  }
}

// ---------------------------------------------------------------------------
extern "C" void kernel_launch(void* const* d_in, const int* in_sizes, int n_in,
                              void* d_out, int out_size, void* d_ws, size_t ws_size,
                              hipStream_t stream) {
  const float* x  = (const float*)d_in[0];
  const float* Wk = (const float*)d_in[1];
  const float* Wq = (const float*)d_in[2];
  const float* Wv = (const float*)d_in[3];
  float* out = (float*)d_out;

  bf16_t* ws  = (bf16_t*)d_ws;
  bf16_t* Wb  = ws + WB_OFF;
  bf16_t* qg  = ws + Q_OFF;
  bf16_t* kg  = ws + K_OFF;
  bf16_t* vTg = ws + VT_OFF;

  wcvt_kernel<<<dim3(192), dim3(256), 0, stream>>>(Wk, Wq, Wv, Wb);
  qkv_proj_kernel<<<dim3(1024), dim3(256), 0, stream>>>(x, Wb, qg, kg, vTg);
  attn_kernel<<<dim3(256), dim3(1024), 0, stream>>>(qg, kg, vTg, out);
}

// Round 8
// 181.876 us; speedup vs baseline: 2.6519x; 1.0113x over previous
//
#include <hip/hip_runtime.h>
#include <math.h>

typedef __bf16 bf16_t;
typedef __bf16 bf16x8 __attribute__((ext_vector_type(8)));
typedef __bf16 bf16x4 __attribute__((ext_vector_type(4)));
typedef float  floatx4 __attribute__((ext_vector_type(4)));

#define TT   4096
#define CD   1024
#define HSZ  64
#define NROW 16384
#define NEG_BIG (-1e30f)

// workspace element offsets (bf16)
#define WB_OFF 0                       // [kc][t12][512]  = 196608 elems
#define Q_OFF  196608                  // q[row][64]
#define K_OFF  (196608 + NROW * HSZ)   // K fragment tiles
#define V_OFF  (196608 + 2 * NROW * HSZ) // V fragment tiles

#if __has_builtin(__builtin_amdgcn_exp2f)
__device__ __forceinline__ float fexp2(float x) { return __builtin_amdgcn_exp2f(x); }
#else
__device__ __forceinline__ float fexp2(float x) { return exp2f(x); }
#endif

// ---- DPP 16-lane allreduce (VALU pipe) ----
template <int CTRL>
__device__ __forceinline__ float dppf(float x) {
  return __builtin_bit_cast(float,
      __builtin_amdgcn_update_dpp(0, __builtin_bit_cast(int, x),
                                  CTRL, 0xF, 0xF, true));
}
__device__ __forceinline__ float rowmax16(float v) {
  v = fmaxf(v, dppf<0xB1>(v));
  v = fmaxf(v, dppf<0x4E>(v));
  v = fmaxf(v, dppf<0x124>(v));
  v = fmaxf(v, dppf<0x128>(v));
  return v;
}
__device__ __forceinline__ float rowsum16(float v) {
  v += dppf<0xB1>(v);
  v += dppf<0x4E>(v);
  v += dppf<0x124>(v);
  v += dppf<0x128>(v);
  return v;
}

// ---------------------------------------------------------------------------
// Kernel 0: fp32 weights -> bf16, layout [kc][t12][512] so a proj block's
// per-kc chunk (all 12 n-tiles' fragments) is one contiguous 12 KB.
// Fragment elem (lane,j) = W_wsel[n = nt*16+(lane&15)][k = kc*32+(lane>>4)*8+j].
// ---------------------------------------------------------------------------
__global__ __launch_bounds__(256, 1) void wcvt_kernel(
    const float* __restrict__ Wk, const float* __restrict__ Wq,
    const float* __restrict__ Wv, bf16_t* __restrict__ Wb)
{
  const int t    = blockIdx.x * 256 + threadIdx.x;  // 192 blocks
  const int e    = t * 4;
  const int tile = e >> 9;          // 0..383
  const int kc   = tile / 12;
  const int t12  = tile - kc * 12;
  const int r    = e & 511;
  const int lane = r >> 3;
  const int j0   = r & 7;
  const int wsel = t12 >> 2;
  const int nt   = t12 & 3;
  const int n    = nt * 16 + (lane & 15);
  const int k    = kc * 32 + (lane >> 4) * 8 + j0;
  const float* src = (wsel == 0) ? Wq : (wsel == 1) ? Wk : Wv;
  float4 f = *(const float4*)(src + n * CD + k);
  bf16x4 o;
  o[0] = (bf16_t)f.x; o[1] = (bf16_t)f.y; o[2] = (bf16_t)f.z; o[3] = (bf16_t)f.w;
  *(bf16x4*)(Wb + e) = o;
}

// ---------------------------------------------------------------------------
// Kernel 1: QKV projection with LDS-shared weights.  512 blocks x 4 waves;
// block owns 32 x-rows.  wave = rg*2+tg: rg = row-group (16 rows), tg picks
// n-tiles t12 = tg*6..tg*6+5.  Per kc a 12 KB weight chunk is staged once
// into LDS (reg double-buffer), shared by all 4 waves -> weight reuse M=32.
// K and V written in MFMA-fragment-contiguous tile layout:
//   K elem (kv,h): ((kv>>6)*4+((kv>>4)&3))*2+(h>>5))*512
//                  + ((h>>3)&3)*128 + (kv&15)*8 + (h&7)
//   V elem (kv,h): ((kv>>6)*2+((kv>>5)&1))*4+(h>>4))*512
//                  + ((kv>>3)&3)*128 + (h&15)*8 + (kv&7)
// so attn's B-fragment loads are contiguous 1 KB per wave.
// ---------------------------------------------------------------------------
__global__ __launch_bounds__(256, 2) void qkv_proj_kernel(
    const float* __restrict__ x, const bf16_t* __restrict__ Wb,
    bf16_t* __restrict__ qg, bf16_t* __restrict__ kfr, bf16_t* __restrict__ vfr)
{
  __shared__ __align__(16) bf16_t wch[6144];   // 12 KB chunk

  const int tid  = threadIdx.x;
  const int lane = tid & 63;
  const int wave = tid >> 6;
  const int mr   = lane & 15;
  const int quad = lane >> 4;
  const int rg   = wave >> 1;
  const int tg   = wave & 1;
  const int m0   = blockIdx.x * 32;

  floatx4 acc[6];
#pragma unroll
  for (int i = 0; i < 6; ++i) acc[i] = (floatx4){0.f, 0.f, 0.f, 0.f};

  const float* xp = x + (size_t)(m0 + rg * 16 + mr) * CD + quad * 8;

  // preload chunk 0 (regs) and x(0)
  bf16x8 wreg[3];
#pragma unroll
  for (int i = 0; i < 3; ++i)
    wreg[i] = *(const bf16x8*)(Wb + i * 2048 + tid * 8);
  float4 xa = *(const float4*)xp;
  float4 xb = *(const float4*)(xp + 4);

  for (int kc = 0; kc < 32; ++kc) {
    if (kc) __syncthreads();           // prior chunk reads done
#pragma unroll
    for (int i = 0; i < 3; ++i)
      *(bf16x8*)&wch[i * 2048 + tid * 8] = wreg[i];
    bf16x8 af;
    af[0]=(bf16_t)xa.x; af[1]=(bf16_t)xa.y; af[2]=(bf16_t)xa.z; af[3]=(bf16_t)xa.w;
    af[4]=(bf16_t)xb.x; af[5]=(bf16_t)xb.y; af[6]=(bf16_t)xb.z; af[7]=(bf16_t)xb.w;
    __syncthreads();                   // chunk kc visible
    if (kc < 31) {                     // prefetch kc+1 (overlaps the MFMAs)
#pragma unroll
      for (int i = 0; i < 3; ++i)
        wreg[i] = *(const bf16x8*)(Wb + (kc + 1) * 6144 + i * 2048 + tid * 8);
      xa = *(const float4*)(xp + (kc + 1) * 32);
      xb = *(const float4*)(xp + (kc + 1) * 32 + 4);
    }
#pragma unroll
    for (int i = 0; i < 6; ++i) {
      bf16x8 wf = *(bf16x8*)&wch[(tg * 6 + i) * 512 + lane * 8];
      acc[i] = __builtin_amdgcn_mfma_f32_16x16x32_bf16(af, wf, acc[i], 0, 0, 0);
    }
  }

  // ---- epilogue.  C/D: row = quad*4+reg (m -> trow), col = mr (n -> h) ----
  const float qscale = 0.18033688011112042f;  // 0.125 * log2(e)
#pragma unroll
  for (int i = 0; i < 6; ++i) {
    const int t12  = tg * 6 + i;
    const int wsel = t12 >> 2;
    const int nt   = t12 & 3;
#pragma unroll
    for (int r = 0; r < 4; ++r) {
      const int trow = m0 + rg * 16 + quad * 4 + r;
      const int h    = nt * 16 + mr;
      const float v  = acc[i][r];
      if (wsel == 0) {
        qg[(size_t)trow * HSZ + h] = (bf16_t)(v * qscale);
      } else if (wsel == 1) {
        const size_t a = ((((size_t)(trow >> 6)) * 4 + ((trow >> 4) & 3)) * 2
                          + (h >> 5)) * 512
                         + ((h >> 3) & 3) * 128 + (trow & 15) * 8 + (h & 7);
        kfr[a] = (bf16_t)v;
      } else {
        const size_t a = ((((size_t)(trow >> 6)) * 2 + ((trow >> 5) & 1)) * 4
                          + (h >> 4)) * 512
                         + ((trow >> 3) & 3) * 128 + (h & 15) * 8 + (trow & 7);
        vfr[a] = (bf16_t)v;
      }
    }
  }
}

// ---------------------------------------------------------------------------
// Kernel 2: causal flash attention.  256 blocks x 1024 thr (16 waves).
// Block owns paired 32-row groups (gA=pr, gB=127-pr) of batch b = bid&3
// (XCD-pinned K/V).  Waves partitioned between groups by KV work; each wave
// owns 32 q-rows (2 subtiles sharing all K/V loads).  K/V loads are
// fragment-contiguous 1 KB streams.
// ---------------------------------------------------------------------------
__global__ __launch_bounds__(1024, 4) void attn_kernel(
    const bf16_t* __restrict__ qg, const bf16_t* __restrict__ kfr,
    const bf16_t* __restrict__ vfr, float* __restrict__ out)
{
  __shared__ __align__(16) char smem[73728];            // plds U cmbo
  __shared__ float cml[16][16][2];
  bf16_t* plds = (bf16_t*)smem;                         // 16 x 2304 elems
  float (*cmbo)[16][68] = (float (*)[16][68])smem;      // [16][16][68]

  const int tid  = threadIdx.x;
  const int lane = tid & 63;
  const int wave = tid >> 6;     // 0..15
  const int mr   = lane & 15;
  const int quad = lane >> 4;

  const int bid = blockIdx.x;    // 0..255
  const int b   = bid & 3;
  const int pr  = bid >> 2;      // 0..63
  const int gA  = pr;
  const int gB  = 127 - pr;
  const int nAw = (gA >> 1) + 1;
  const int nBw = (gB >> 1) + 1;
  int na = (16 * nAw + ((nAw + nBw) >> 1)) / (nAw + nBw);
  na = na < 1 ? 1 : (na > 15 ? 15 : na);

  const bool inA   = wave < na;
  const int g      = inA ? gA : gB;
  const int slot   = inA ? wave : wave - na;
  const int nsplit = inA ? na : 16 - na;
  const int q0     = g * 32;
  const int ktmax  = g >> 1;

  const size_t baseq = (size_t)b * TT * HSZ;
  const bf16_t* kb = kfr + (size_t)b * 64 * 4096;   // 64 tiles x 4096 elems
  const bf16_t* vb = vfr + (size_t)b * 64 * 4096;

  bf16_t* pl0 = plds + wave * 2304;
  bf16_t* pl1 = pl0 + 1152;

  bf16x8 qf[2][2];
#pragma unroll
  for (int s = 0; s < 2; ++s) {
    const bf16_t* qp = qg + baseq + (size_t)(q0 + s * 16 + mr) * HSZ + quad * 8;
    qf[s][0] = *(const bf16x8*)qp;
    qf[s][1] = *(const bf16x8*)(qp + 32);
  }

  floatx4 o0[4], o1[4];
#pragma unroll
  for (int i = 0; i < 4; ++i) {
    o0[i] = (floatx4){0.f, 0.f, 0.f, 0.f};
    o1[i] = (floatx4){0.f, 0.f, 0.f, 0.f};
  }
  float mst[2][4], lst[2][4];
#pragma unroll
  for (int s = 0; s < 2; ++s)
#pragma unroll
    for (int r = 0; r < 4; ++r) { mst[s][r] = NEG_BIG; lst[s][r] = 0.f; }

  for (int kt = slot; kt <= ktmax; kt += nsplit) {
    const int k0 = kt * 64;

    // ---- S for both subtiles; K fragments contiguous 1 KB each ----
    floatx4 s0[4], s1[4];
#pragma unroll
    for (int i = 0; i < 4; ++i) {
      s0[i] = (floatx4){0.f, 0.f, 0.f, 0.f};
      s1[i] = (floatx4){0.f, 0.f, 0.f, 0.f};
    }
#pragma unroll
    for (int nt = 0; nt < 4; ++nt) {
      const bf16_t* kp = kb + ((size_t)kt * 4 + nt) * 1024 + lane * 8;
      bf16x8 kb0 = *(const bf16x8*)kp;          // half 0 (h 0..31)
      bf16x8 kb1 = *(const bf16x8*)(kp + 512);  // half 1 (h 32..63)
      s0[nt] = __builtin_amdgcn_mfma_f32_16x16x32_bf16(qf[0][0], kb0, s0[nt], 0, 0, 0);
      s0[nt] = __builtin_amdgcn_mfma_f32_16x16x32_bf16(qf[0][1], kb1, s0[nt], 0, 0, 0);
      s1[nt] = __builtin_amdgcn_mfma_f32_16x16x32_bf16(qf[1][0], kb0, s1[nt], 0, 0, 0);
      s1[nt] = __builtin_amdgcn_mfma_f32_16x16x32_bf16(qf[1][1], kb1, s1[nt], 0, 0, 0);
    }

    // ---- causal mask (last tile only) ----
    if (kt == ktmax) {
#pragma unroll
      for (int nt = 0; nt < 4; ++nt) {
        const int col = k0 + nt * 16 + mr;
#pragma unroll
        for (int r = 0; r < 4; ++r) {
          const int row0 = q0 + quad * 4 + r;
          if (col > row0)      s0[nt][r] = NEG_BIG;
          if (col > row0 + 16) s1[nt][r] = NEG_BIG;
        }
      }
    }

    // ---- softmax subtile 0 -> P0 ----
#pragma unroll
    for (int r = 0; r < 4; ++r) {
      float mx = fmaxf(fmaxf(s0[0][r], s0[1][r]), fmaxf(s0[2][r], s0[3][r]));
      mx = rowmax16(mx);
      const float mnew  = fmaxf(mst[0][r], mx);
      const float alpha = fexp2(mst[0][r] - mnew);
      mst[0][r] = mnew;
      float rs = 0.f;
#pragma unroll
      for (int nt = 0; nt < 4; ++nt) {
        const float pv = fexp2(s0[nt][r] - mnew);
        s0[nt][r] = pv;
        rs += pv;
      }
      lst[0][r] = alpha * lst[0][r] + rs;
#pragma unroll
      for (int nt = 0; nt < 4; ++nt) o0[nt][r] *= alpha;
    }
#pragma unroll
    for (int nt = 0; nt < 4; ++nt)
#pragma unroll
      for (int r = 0; r < 4; ++r)
        pl0[(quad * 4 + r) * 72 + nt * 16 + mr] = (bf16_t)s0[nt][r];

    // ---- V fragment loads (contiguous 1 KB each; shared by subtiles) ----
    bf16x8 vfa[4], vfb[4];
#pragma unroll
    for (int nt = 0; nt < 4; ++nt) {
      const bf16_t* vp = vb + ((size_t)kt * 8 + nt) * 512 + lane * 8;
      vfa[nt] = *(const bf16x8*)vp;              // kc-half 0 (kv 0..31)
      vfb[nt] = *(const bf16x8*)(vp + 2048);     // kc-half 1 (kv 32..63)
    }

    // ---- softmax subtile 1 -> P1 ----
#pragma unroll
    for (int r = 0; r < 4; ++r) {
      float mx = fmaxf(fmaxf(s1[0][r], s1[1][r]), fmaxf(s1[2][r], s1[3][r]));
      mx = rowmax16(mx);
      const float mnew  = fmaxf(mst[1][r], mx);
      const float alpha = fexp2(mst[1][r] - mnew);
      mst[1][r] = mnew;
      float rs = 0.f;
#pragma unroll
      for (int nt = 0; nt < 4; ++nt) {
        const float pv = fexp2(s1[nt][r] - mnew);
        s1[nt][r] = pv;
        rs += pv;
      }
      lst[1][r] = alpha * lst[1][r] + rs;
#pragma unroll
      for (int nt = 0; nt < 4; ++nt) o1[nt][r] *= alpha;
    }
#pragma unroll
    for (int nt = 0; nt < 4; ++nt)
#pragma unroll
      for (int r = 0; r < 4; ++r)
        pl1[(quad * 4 + r) * 72 + nt * 16 + mr] = (bf16_t)s1[nt][r];

    // ---- O += P V ----
#pragma unroll
    for (int kc = 0; kc < 2; ++kc) {
      bf16x8 af0 = *(bf16x8*)&pl0[mr * 72 + kc * 32 + quad * 8];
      bf16x8 af1 = *(bf16x8*)&pl1[mr * 72 + kc * 32 + quad * 8];
#pragma unroll
      for (int nt = 0; nt < 4; ++nt) {
        bf16x8 vf = kc ? vfb[nt] : vfa[nt];
        o0[nt] = __builtin_amdgcn_mfma_f32_16x16x32_bf16(af0, vf, o0[nt], 0, 0, 0);
        o1[nt] = __builtin_amdgcn_mfma_f32_16x16x32_bf16(af1, vf, o1[nt], 0, 0, 0);
      }
    }
  }

  // ---- combine: per group over its wave-slots, one subtile per pass ----
  __syncthreads();   // all PV reads of plds done (cmbo overlays it)
#pragma unroll
  for (int s = 0; s < 2; ++s) {
    float lsum[4];
#pragma unroll
    for (int r = 0; r < 4; ++r) lsum[r] = rowsum16(lst[s][r]);
    if (mr == 0) {
#pragma unroll
      for (int r = 0; r < 4; ++r) {
        cml[wave][quad * 4 + r][0] = mst[s][r];
        cml[wave][quad * 4 + r][1] = lsum[r];
      }
    }
    __syncthreads();
    {
      const int lo = inA ? 0 : na;
      const int hi = inA ? na : 16;
#pragma unroll
      for (int r = 0; r < 4; ++r) {
        const int row = quad * 4 + r;
        float mstar = cml[lo][row][0];
        for (int i = lo + 1; i < hi; ++i) mstar = fmaxf(mstar, cml[i][row][0]);
        const float scale = fexp2(mst[s][r] - mstar);
#pragma unroll
        for (int nt = 0; nt < 4; ++nt)
          cmbo[wave][row][nt * 16 + mr] = (s ? o1[nt][r] : o0[nt][r]) * scale;
      }
    }
    __syncthreads();
    {
      const int grp = tid >> 9;            // 0 = A, 1 = B
      const int row = (tid >> 5) & 15;
      const int c0  = (tid & 31) * 2;
      const int lo  = grp ? na : 0;
      const int hi  = grp ? 16 : na;
      const int gq0 = (grp ? gB : gA) * 32 + s * 16;
      float mstar = cml[lo][row][0];
      for (int i = lo + 1; i < hi; ++i) mstar = fmaxf(mstar, cml[i][row][0]);
      float l = 0.f;
      for (int i = lo; i < hi; ++i)
        l += cml[i][row][1] * fexp2(cml[i][row][0] - mstar);
      float sx = 0.f, sy = 0.f;
      for (int i = lo; i < hi; ++i) {
        float2 v = *(float2*)&cmbo[i][row][c0];
        sx += v.x; sy += v.y;
      }
      const float invl = 1.0f / l;
      float2 res; res.x = sx * invl; res.y = sy * invl;
      *(float2*)(out + baseq + (size_t)(gq0 + row) * HSZ + c0) = res;
    }
    __syncthreads();   // cml/cmbo reused by next pass
  }
}

// ---------------------------------------------------------------------------
extern "C" void kernel_launch(void* const* d_in, const int* in_sizes, int n_in,
                              void* d_out, int out_size, void* d_ws, size_t ws_size,
                              hipStream_t stream) {
  const float* x  = (const float*)d_in[0];
  const float* Wk = (const float*)d_in[1];
  const float* Wq = (const float*)d_in[2];
  const float* Wv = (const float*)d_in[3];
  float* out = (float*)d_out;

  bf16_t* ws  = (bf16_t*)d_ws;
  bf16_t* Wb  = ws + WB_OFF;
  bf16_t* qg  = ws + Q_OFF;
  bf16_t* kfr = ws + K_OFF;
  bf16_t* vfr = ws + V_OFF;

  wcvt_kernel<<<dim3(192), dim3(256), 0, stream>>>(Wk, Wq, Wv, Wb);
  qkv_proj_kernel<<<dim3(512), dim3(256), 0, stream>>>(x, Wb, qg, kfr, vfr);
  attn_kernel<<<dim3(256), dim3(1024), 0, stream>>>(qg, kfr, vfr, out);
}